// Round 1
// baseline (886.558 us; speedup 1.0000x reference)
//
#include <hip/hip_runtime.h>

// ---------------------------------------------------------------------------
// GAT x3 + ReLU + BatchNorm, MI355X. Strategy:
//   - Build CSR (by dst, incl. self-loops) ONCE; reused by all 3 layers.
//   - Per layer: fp32 tiled GEMM -> attention logits -> per-dst-wave
//     online-softmax aggregation (no atomics) -> BN stats -> BN apply
//     (writes both next-layer input and the strided d_out slice).
// ---------------------------------------------------------------------------

// ---------------- CSR build ----------------
__global__ void k_set1(int* __restrict__ p, int n) {
    int i = blockIdx.x * blockDim.x + threadIdx.x;
    if (i < n) p[i] = 1;   // self-loop contributes degree 1
}

__global__ void k_deg_count(const int* __restrict__ dst, int e, int* __restrict__ deg) {
    int i = blockIdx.x * blockDim.x + threadIdx.x;
    if (i < e) atomicAdd(&deg[dst[i]], 1);
}

// single-block exclusive scan over n elements (n ~ 50k: ~49 chunks of 1024)
__global__ void k_scan(const int* __restrict__ deg, int* __restrict__ row_start, int n) {
    __shared__ int s[1024];
    __shared__ int carry_s;
    if (threadIdx.x == 0) carry_s = 0;
    __syncthreads();
    for (int base = 0; base < n; base += 1024) {
        int i = base + (int)threadIdx.x;
        int v = (i < n) ? deg[i] : 0;
        s[threadIdx.x] = v;
        __syncthreads();
        for (int off = 1; off < 1024; off <<= 1) {
            int t = (threadIdx.x >= (unsigned)off) ? s[threadIdx.x - off] : 0;
            __syncthreads();
            s[threadIdx.x] += t;
            __syncthreads();
        }
        if (i < n) row_start[i] = carry_s + (s[threadIdx.x] - v);
        __syncthreads();
        if (threadIdx.x == 1023) carry_s += s[1023];
        __syncthreads();
    }
    if (threadIdx.x == 0) row_start[n] = carry_s;
}

__global__ void k_copy_int(const int* __restrict__ a, int* __restrict__ b, int n) {
    int i = blockIdx.x * blockDim.x + threadIdx.x;
    if (i < n) b[i] = a[i];
}

__global__ void k_fill(const int* __restrict__ src, const int* __restrict__ dst,
                       int e, int n, int* __restrict__ cursor, int* __restrict__ col) {
    int i = blockIdx.x * blockDim.x + threadIdx.x;
    if (i < e) {
        int d = dst[i];
        int p = atomicAdd(&cursor[d], 1);
        col[p] = src[i];
    } else if (i < e + n) {
        int v = i - e;                // self-loop
        int p = atomicAdd(&cursor[v], 1);
        col[p] = v;
    }
}

// ---------------- GEMM: C[M,F] = A[M,128] @ W[128,F] ----------------
template <int F>
__global__ __launch_bounds__(256) void k_gemm(const float* __restrict__ A,
                                              const float* __restrict__ W,
                                              float* __restrict__ C, int M) {
    constexpr int K = 128;
    constexpr int TN = F / 16;           // 8 (F=128) or 4 (F=64)
    __shared__ float As[32][65];         // [kk][row], +1 pad
    __shared__ float Ws[32][F];          // [kk][col]
    int tid = threadIdx.x;
    int tx = tid & 15, ty = tid >> 4;
    int rowBase = blockIdx.x * 64;

    float acc[4][TN];
#pragma unroll
    for (int i = 0; i < 4; i++)
#pragma unroll
        for (int j = 0; j < TN; j++) acc[i][j] = 0.f;

    for (int k0 = 0; k0 < K; k0 += 32) {
        int c = tid & 31, rg = tid >> 5;       // A tile: 64 rows x 32 k
#pragma unroll
        for (int i = 0; i < 8; i++) {
            int r = rg + i * 8;
            int grow = rowBase + r;
            As[c][r] = (grow < M) ? A[(long long)grow * K + k0 + c] : 0.f;
        }
        if (F == 128) {
            int cc = tid & 127, g = tid >> 7;  // W tile: 32 x 128
#pragma unroll
            for (int j = 0; j < 16; j++) {
                int kk = g + j * 2;
                Ws[kk][cc] = W[(k0 + kk) * F + cc];
            }
        } else {
            int cc = tid & 63, g = tid >> 6;   // W tile: 32 x 64
#pragma unroll
            for (int j = 0; j < 8; j++) {
                int kk = g + j * 4;
                Ws[kk][cc] = W[(k0 + kk) * F + cc];
            }
        }
        __syncthreads();
#pragma unroll
        for (int kk = 0; kk < 32; ++kk) {
            float a0[4], w0[TN];
#pragma unroll
            for (int i = 0; i < 4; i++) a0[i] = As[kk][ty * 4 + i];
#pragma unroll
            for (int j = 0; j < TN; j++) w0[j] = Ws[kk][tx * TN + j];
#pragma unroll
            for (int i = 0; i < 4; i++)
#pragma unroll
                for (int j = 0; j < TN; j++) acc[i][j] += a0[i] * w0[j];
        }
        __syncthreads();
    }
#pragma unroll
    for (int i = 0; i < 4; i++) {
        int grow = rowBase + ty * 4 + i;
        if (grow < M) {
#pragma unroll
            for (int j = 0; j < TN; j++)
                C[(long long)grow * F + tx * TN + j] = acc[i][j];
        }
    }
}

// ---------------- attention logits: al_s/al_d [N,H] ----------------
template <int F, int H>
__global__ void k_attn(const float* __restrict__ xw, const float* __restrict__ asrc,
                       const float* __restrict__ adst, float* __restrict__ al_s,
                       float* __restrict__ al_d, int n) {
    int t = blockIdx.x * blockDim.x + threadIdx.x;
    int node = t / F;
    if (node >= n) return;
    int ch = t % F;
    int h = ch >> 6, c = ch & 63;
    float x = xw[(long long)node * F + ch];
    float ps = x * asrc[h * 64 + c];
    float pd = x * adst[h * 64 + c];
#pragma unroll
    for (int off = 32; off; off >>= 1) {
        ps += __shfl_down(ps, off);
        pd += __shfl_down(pd, off);
    }
    if (c == 0) {
        al_s[node * H + h] = ps;
        al_d[node * H + h] = pd;
    }
}

// ---------------- per-dst-wave softmax aggregation (+bias+ReLU) ----------------
template <int F, int H>
__global__ void k_agg(const float* __restrict__ xw, const float* __restrict__ al_s,
                      const float* __restrict__ al_d, const int* __restrict__ row_start,
                      const int* __restrict__ col, const float* __restrict__ bias,
                      float* __restrict__ y, int n) {
    int wid = (blockIdx.x * blockDim.x + threadIdx.x) >> 6;  // one wave per dst
    int lane = threadIdx.x & 63;
    if (wid >= n) return;
    int dst = wid;
    int beg = row_start[dst], end = row_start[dst + 1];

    float ald[H], m[H], l[H];
#pragma unroll
    for (int h = 0; h < H; h++) {
        ald[h] = al_d[dst * H + h];
        m[h] = -1e30f;
        l[h] = 0.f;
    }
    // phase 1: online max+sum over incoming edges (lanes split edges)
    for (int e = beg + lane; e < end; e += 64) {
        int s = col[e];
#pragma unroll
        for (int h = 0; h < H; h++) {
            float ev = al_s[s * H + h] + ald[h];
            ev = (ev >= 0.f) ? ev : 0.2f * ev;          // leaky_relu(0.2)
            if (ev > m[h]) {
                l[h] = l[h] * __expf(m[h] - ev) + 1.f;
                m[h] = ev;
            } else {
                l[h] += __expf(ev - m[h]);
            }
        }
    }
    // cross-lane merge (butterfly over 64 lanes)
#pragma unroll
    for (int off = 32; off; off >>= 1) {
#pragma unroll
        for (int h = 0; h < H; h++) {
            float mo = __shfl_xor(m[h], off);
            float lo = __shfl_xor(l[h], off);
            float mn = fmaxf(m[h], mo);
            l[h] = l[h] * __expf(m[h] - mn) + lo * __expf(mo - mn);
            m[h] = mn;
        }
    }
    float inv[H];
#pragma unroll
    for (int h = 0; h < H; h++) inv[h] = 1.f / (l[h] + 1e-16f);

    // phase 2: weighted gather. lane owns channel h*64+lane for each head.
    float acc[H];
#pragma unroll
    for (int h = 0; h < H; h++) acc[h] = 0.f;
    for (int e = beg; e < end; ++e) {
        int s = col[e];  // wave-uniform -> broadcast load
#pragma unroll
        for (int h = 0; h < H; h++) {
            float ev = al_s[s * H + h] + ald[h];
            ev = (ev >= 0.f) ? ev : 0.2f * ev;
            float alpha = __expf(ev - m[h]) * inv[h];
            acc[h] += alpha * xw[(long long)s * F + h * 64 + lane];
        }
    }
#pragma unroll
    for (int h = 0; h < H; h++) {
        float v = acc[h] + bias[h * 64 + lane];
        y[(long long)dst * F + h * 64 + lane] = fmaxf(v, 0.f);  // fused ReLU
    }
}

// ---------------- BatchNorm ----------------
template <int F>
__global__ void k_bn_stats(const float* __restrict__ y, float* __restrict__ sums, int n) {
    constexpr int NPB = 256 / F;
    int ch = threadIdx.x % F;
    int sub = threadIdx.x / F;
    float s = 0.f, s2 = 0.f;
    for (int node = blockIdx.x * NPB + sub; node < n; node += gridDim.x * NPB) {
        float v = y[(long long)node * F + ch];
        s += v;
        s2 += v * v;
    }
    __shared__ float ls[256], ls2[256];
    ls[threadIdx.x] = s;
    ls2[threadIdx.x] = s2;
    __syncthreads();
    if (sub == 0) {
#pragma unroll
        for (int k = 1; k < NPB; k++) {
            s += ls[ch + k * F];
            s2 += ls2[ch + k * F];
        }
        atomicAdd(&sums[ch], s);
        atomicAdd(&sums[F + ch], s2);
    }
}

template <int F>
__global__ void k_bn_apply(const float* __restrict__ y, const float* __restrict__ sums,
                           const float* __restrict__ g, const float* __restrict__ be,
                           float* __restrict__ xnext, float* __restrict__ outp,
                           int n, float invN) {
    int t = blockIdx.x * blockDim.x + threadIdx.x;
    if (t >= n * F) return;
    int node = t / F, ch = t % F;
    float mean = sums[ch] * invN;
    float var = sums[F + ch] * invN - mean * mean;
    float sc = g[ch] * rsqrtf(var + 1e-5f);
    float val = (y[t] - mean) * sc + be[ch];
    if (xnext) xnext[t] = val;
    outp[(long long)node * 320 + ch] = val;   // strided slice of d_out
}

// ---------------------------------------------------------------------------
extern "C" void kernel_launch(void* const* d_in, const int* in_sizes, int n_in,
                              void* d_out, int out_size, void* d_ws, size_t ws_size,
                              hipStream_t stream) {
    const float* x   = (const float*)d_in[0];
    const int*   adj = (const int*)d_in[1];
    const float* W1  = (const float*)d_in[2];
    const float* as1 = (const float*)d_in[3];
    const float* ad1 = (const float*)d_in[4];
    const float* b1  = (const float*)d_in[5];
    const float* g1  = (const float*)d_in[6];
    const float* be1 = (const float*)d_in[7];
    const float* W2  = (const float*)d_in[8];
    const float* as2 = (const float*)d_in[9];
    const float* ad2 = (const float*)d_in[10];
    const float* b2  = (const float*)d_in[11];
    const float* g2  = (const float*)d_in[12];
    const float* be2 = (const float*)d_in[13];
    const float* W3  = (const float*)d_in[14];
    const float* as3 = (const float*)d_in[15];
    const float* ad3 = (const float*)d_in[16];
    const float* b3  = (const float*)d_in[17];
    const float* g3  = (const float*)d_in[18];
    const float* be3 = (const float*)d_in[19];
    float* out = (float*)d_out;

    const int N = in_sizes[0] / 128;
    const int E = in_sizes[1] / 2;

    // workspace layout (floats then ints)
    float* ws    = (float*)d_ws;
    float* xw    = ws;                          // N*128
    float* ybuf  = xw + (size_t)N * 128;        // N*128
    float* xbuf  = ybuf + (size_t)N * 128;      // N*128
    float* al_s  = xbuf + (size_t)N * 128;      // N*2
    float* al_d  = al_s + (size_t)N * 2;        // N*2
    float* stats = al_d + (size_t)N * 2;        // 256
    int* deg       = (int*)(stats + 256);       // N
    int* row_start = deg + N;                   // N+1
    int* cursor    = row_start + (N + 1);       // N
    int* col       = cursor + N;                // E+N

    const int* esrc = adj;
    const int* edst = adj + E;

    const int B = 256;
    auto cdiv = [](int a, int b) { return (a + b - 1) / b; };

    // ---- CSR build (graph shared by all layers) ----
    k_set1<<<cdiv(N, B), B, 0, stream>>>(deg, N);
    k_deg_count<<<cdiv(E, B), B, 0, stream>>>(edst, E, deg);
    k_scan<<<1, 1024, 0, stream>>>(deg, row_start, N);
    k_copy_int<<<cdiv(N, B), B, 0, stream>>>(row_start, cursor, N);
    k_fill<<<cdiv(E + N, B), B, 0, stream>>>(esrc, edst, E, N, cursor, col);

    const float invN = 1.f / (float)N;

    // ---- layer 1: 128 -> 128 (H=2) ----
    k_gemm<128><<<cdiv(N, 64), B, 0, stream>>>(x, W1, xw, N);
    k_attn<128, 2><<<cdiv(N * 128, B), B, 0, stream>>>(xw, as1, ad1, al_s, al_d, N);
    k_agg<128, 2><<<cdiv(N, 4), B, 0, stream>>>(xw, al_s, al_d, row_start, col, b1, ybuf, N);
    hipMemsetAsync(stats, 0, 256 * sizeof(float), stream);
    k_bn_stats<128><<<1024, B, 0, stream>>>(ybuf, stats, N);
    k_bn_apply<128><<<cdiv(N * 128, B), B, 0, stream>>>(ybuf, stats, g1, be1, xbuf, out + 0, N, invN);

    // ---- layer 2: 128 -> 128 (H=2) ----
    k_gemm<128><<<cdiv(N, 64), B, 0, stream>>>(xbuf, W2, xw, N);
    k_attn<128, 2><<<cdiv(N * 128, B), B, 0, stream>>>(xw, as2, ad2, al_s, al_d, N);
    k_agg<128, 2><<<cdiv(N, 4), B, 0, stream>>>(xw, al_s, al_d, row_start, col, b2, ybuf, N);
    hipMemsetAsync(stats, 0, 256 * sizeof(float), stream);
    k_bn_stats<128><<<1024, B, 0, stream>>>(ybuf, stats, N);
    k_bn_apply<128><<<cdiv(N * 128, B), B, 0, stream>>>(ybuf, stats, g2, be2, xbuf, out + 128, N, invN);

    // ---- layer 3: 128 -> 64 (H=1) ----
    k_gemm<64><<<cdiv(N, 64), B, 0, stream>>>(xbuf, W3, xw, N);
    k_attn<64, 1><<<cdiv(N * 64, B), B, 0, stream>>>(xw, as3, ad3, al_s, al_d, N);
    k_agg<64, 1><<<cdiv(N, 4), B, 0, stream>>>(xw, al_s, al_d, row_start, col, b3, ybuf, N);
    hipMemsetAsync(stats, 0, 256 * sizeof(float), stream);
    k_bn_stats<64><<<1024, B, 0, stream>>>(ybuf, stats, N);
    k_bn_apply<64><<<cdiv(N * 64, B), B, 0, stream>>>(ybuf, stats, g3, be3, nullptr, out + 256, N, invN);
}

// Round 2
// 698.282 us; speedup vs baseline: 1.2696x; 1.2696x over previous
//
#include <hip/hip_runtime.h>

// ---------------------------------------------------------------------------
// GAT x3 + ReLU + BatchNorm, MI355X.
//   - CSR by dst (incl. self-loops) built once, hierarchical scan.
//   - Per layer: GEMM (BN of previous layer folded into A-staging) ->
//     attention logits -> per-dst-wave softmax aggregation with shuffled
//     wave-uniform alphas + float2 gather -> BN stats/prep -> BN apply to out.
// ---------------------------------------------------------------------------

__global__ void k_set1(int* __restrict__ p, int n) {
    int i = blockIdx.x * blockDim.x + threadIdx.x;
    if (i < n) p[i] = 1;   // self-loop
}

__global__ void k_deg_count(const int* __restrict__ dst, int e, int* __restrict__ deg) {
    int i = blockIdx.x * blockDim.x + threadIdx.x;
    if (i < e) atomicAdd(&deg[dst[i]], 1);
}

// ---- hierarchical exclusive scan: per-block scan + block offsets ----
__global__ void k_scan1(const int* __restrict__ deg, int* __restrict__ rs,
                        int* __restrict__ btot, int n) {
    __shared__ int s[1024];
    int tid = threadIdx.x;
    int i = blockIdx.x * 1024 + tid;
    int v = (i < n) ? deg[i] : 0;
    s[tid] = v;
    __syncthreads();
    for (int off = 1; off < 1024; off <<= 1) {
        int t = (tid >= off) ? s[tid - off] : 0;
        __syncthreads();
        s[tid] += t;
        __syncthreads();
    }
    if (i < n) rs[i] = s[tid] - v;          // exclusive within block
    if (tid == 1023) btot[blockIdx.x] = s[1023];
}

__global__ void k_scan2(int* __restrict__ btot, int nb, int* __restrict__ rs, int n) {
    if (threadIdx.x == 0 && blockIdx.x == 0) {
        int acc = 0;
        for (int i = 0; i < nb; i++) { int t = btot[i]; btot[i] = acc; acc += t; }
        rs[n] = acc;                         // sentinel = total (E+N)
    }
}

__global__ void k_scan3(int* __restrict__ rs, const int* __restrict__ btot, int n) {
    int i = blockIdx.x * 1024 + threadIdx.x;
    if (i < n) rs[i] += btot[blockIdx.x];
}

__global__ void k_copy_int(const int* __restrict__ a, int* __restrict__ b, int n) {
    int i = blockIdx.x * blockDim.x + threadIdx.x;
    if (i < n) b[i] = a[i];
}

__global__ void k_fill(const int* __restrict__ src, const int* __restrict__ dst,
                       int e, int n, int* __restrict__ cursor, int* __restrict__ col) {
    int i = blockIdx.x * blockDim.x + threadIdx.x;
    if (i < e) {
        int d = dst[i];
        int p = atomicAdd(&cursor[d], 1);
        col[p] = src[i];
    } else if (i < e + n) {
        int v = i - e;                      // self-loop
        int p = atomicAdd(&cursor[v], 1);
        col[p] = v;
    }
}

// ---------------- GEMM: C[M,F] = BN(A)[M,128] @ W[128,F] ----------------
template <int F, bool BN>
__global__ __launch_bounds__(256) void k_gemm(const float* __restrict__ A,
                                              const float* __restrict__ W,
                                              const float* __restrict__ sc,
                                              const float* __restrict__ sh,
                                              float* __restrict__ C, int M) {
    constexpr int K = 128;
    constexpr int TN = F / 16;           // 8 (F=128) or 4 (F=64)
    __shared__ float As[32][65];
    __shared__ float Ws[32][F];
    int tid = threadIdx.x;
    int tx = tid & 15, ty = tid >> 4;
    int rowBase = blockIdx.x * 64;

    float acc[4][TN];
#pragma unroll
    for (int i = 0; i < 4; i++)
#pragma unroll
        for (int j = 0; j < TN; j++) acc[i][j] = 0.f;

    for (int k0 = 0; k0 < K; k0 += 32) {
        int c = tid & 31, rg = tid >> 5;
        float scv = BN ? sc[k0 + c] : 1.f;
        float shv = BN ? sh[k0 + c] : 0.f;
#pragma unroll
        for (int i = 0; i < 8; i++) {
            int r = rg + i * 8;
            int grow = rowBase + r;
            float a = (grow < M) ? A[(long long)grow * K + k0 + c] : 0.f;
            As[c][r] = (grow < M) ? (BN ? fmaf(a, scv, shv) : a) : 0.f;
        }
        if (F == 128) {
            int cc = tid & 127, g = tid >> 7;
#pragma unroll
            for (int j = 0; j < 16; j++) {
                int kk = g + j * 2;
                Ws[kk][cc] = W[(k0 + kk) * F + cc];
            }
        } else {
            int cc = tid & 63, g = tid >> 6;
#pragma unroll
            for (int j = 0; j < 8; j++) {
                int kk = g + j * 4;
                Ws[kk][cc] = W[(k0 + kk) * F + cc];
            }
        }
        __syncthreads();
#pragma unroll
        for (int kk = 0; kk < 32; ++kk) {
            float a0[4], w0[TN];
#pragma unroll
            for (int i = 0; i < 4; i++) a0[i] = As[kk][ty * 4 + i];
#pragma unroll
            for (int j = 0; j < TN; j++) w0[j] = Ws[kk][tx * TN + j];
#pragma unroll
            for (int i = 0; i < 4; i++)
#pragma unroll
                for (int j = 0; j < TN; j++) acc[i][j] += a0[i] * w0[j];
        }
        __syncthreads();
    }
#pragma unroll
    for (int i = 0; i < 4; i++) {
        int grow = rowBase + ty * 4 + i;
        if (grow < M) {
#pragma unroll
            for (int j = 0; j < TN; j++)
                C[(long long)grow * F + tx * TN + j] = acc[i][j];
        }
    }
}

// ---------------- attention logits: al_s/al_d [N,H], float2 loads ----------------
template <int F, int H>
__global__ void k_attn(const float* __restrict__ xw, const float* __restrict__ asrc,
                       const float* __restrict__ adst, float* __restrict__ al_s,
                       float* __restrict__ al_d, int n) {
    int t = blockIdx.x * blockDim.x + threadIdx.x;
    constexpr int C2 = F / 2;                     // float2s per node
    int node = t / C2;
    if (node >= n) return;
    int c2 = t % C2;                              // channels {2c2, 2c2+1}
    float2 x = ((const float2*)xw)[(long long)node * C2 + c2];
    float ps = x.x * asrc[2 * c2] + x.y * asrc[2 * c2 + 1];
    float pd = x.x * adst[2 * c2] + x.y * adst[2 * c2 + 1];
    // reduce over 32 consecutive lanes (one head's 64 channels = 32 float2 lanes)
#pragma unroll
    for (int off = 16; off; off >>= 1) {
        ps += __shfl_xor(ps, off);
        pd += __shfl_xor(pd, off);
    }
    if ((c2 & 31) == 0) {
        int h = (2 * c2) >> 6;                    // head of this 32-lane group
        al_s[node * H + h] = ps;
        al_d[node * H + h] = pd;
    }
}

// ---------------- per-dst-wave softmax aggregation (+bias+ReLU) ----------------
template <int F, int H>
__global__ __launch_bounds__(256) void k_agg(const float* __restrict__ xw,
                      const float* __restrict__ al_s,
                      const float* __restrict__ al_d, const int* __restrict__ row_start,
                      const int* __restrict__ col, const float* __restrict__ bias,
                      float* __restrict__ y, int n) {
    int wid = (blockIdx.x * blockDim.x + threadIdx.x) >> 6;  // one wave per dst
    int lane = threadIdx.x & 63;
    if (wid >= n) return;
    int beg = row_start[wid], end = row_start[wid + 1];

    float ald[H], m[H], l[H];
#pragma unroll
    for (int h = 0; h < H; h++) {
        ald[h] = al_d[wid * H + h];
        m[h] = -1e30f;
        l[h] = 0.f;
    }
    // phase 1: online max+sum (lanes split edges)
    for (int e = beg + lane; e < end; e += 64) {
        int s = col[e];
#pragma unroll
        for (int h = 0; h < H; h++) {
            float ev = al_s[s * H + h] + ald[h];
            ev = (ev >= 0.f) ? ev : 0.2f * ev;
            if (ev > m[h]) {
                l[h] = l[h] * __expf(m[h] - ev) + 1.f;
                m[h] = ev;
            } else {
                l[h] += __expf(ev - m[h]);
            }
        }
    }
#pragma unroll
    for (int off = 32; off; off >>= 1) {
#pragma unroll
        for (int h = 0; h < H; h++) {
            float mo = __shfl_xor(m[h], off);
            float lo = __shfl_xor(l[h], off);
            float mn = fmaxf(m[h], mo);
            l[h] = l[h] * __expf(m[h] - mn) + lo * __expf(mo - mn);
            m[h] = mn;
        }
    }
    float inv[H];
#pragma unroll
    for (int h = 0; h < H; h++) inv[h] = 1.f / (l[h] + 1e-16f);

    // phase 2: lane owns channels {2*lane, 2*lane+1} (F=128) or {lane} (F=64).
    // Alphas computed once per edge (lane-parallel), broadcast via shuffles.
    float acc0 = 0.f, acc1 = 0.f;
    const float2* xw2 = (const float2*)xw;
    for (int base = beg; base < end; base += 64) {
        int nb = min(64, end - base);
        int ec = min(base + lane, end - 1);       // clamp: extra lanes unused
        int s = col[ec];
        float a0, a1;
        {
            float av[H];
#pragma unroll
            for (int h = 0; h < H; h++) {
                float ev = al_s[s * H + h] + ald[h];
                ev = (ev >= 0.f) ? ev : 0.2f * ev;
                av[h] = __expf(ev - m[h]) * inv[h];
            }
            a0 = av[0];
            a1 = av[H - 1];
        }
        for (int j = 0; j < nb; ++j) {
            int sj = __shfl(s, j);
            float p0 = __shfl(a0, j);
            float alpha;
            if (H == 2) {
                float p1 = __shfl(a1, j);
                alpha = (lane < 32) ? p0 : p1;    // head = lane>>5 (ch 2*lane)
            } else {
                alpha = p0;
            }
            if (F == 128) {
                float2 v = xw2[(sj << 6) + lane];
                acc0 = fmaf(alpha, v.x, acc0);
                acc1 = fmaf(alpha, v.y, acc1);
            } else {
                float v = xw[(sj << 6) + lane];
                acc0 = fmaf(alpha, v, acc0);
            }
        }
    }
    if (F == 128) {
        float2 o;
        o.x = fmaxf(acc0 + bias[2 * lane], 0.f);
        o.y = fmaxf(acc1 + bias[2 * lane + 1], 0.f);
        ((float2*)y)[(long long)wid * 64 + lane] = o;
    } else {
        y[(long long)wid * 64 + lane] = fmaxf(acc0 + bias[lane], 0.f);
    }
}

// ---------------- BatchNorm ----------------
template <int F>
__global__ void k_bn_stats(const float* __restrict__ y, float* __restrict__ sums, int n) {
    constexpr int C4 = F / 4;                 // float4s per node: 32 or 16
    constexpr int NPB = 256 / C4;             // nodes in flight per block
    int c4 = threadIdx.x % C4;
    int sub = threadIdx.x / C4;
    float4 s = {0, 0, 0, 0}, s2 = {0, 0, 0, 0};
    for (int node = blockIdx.x * NPB + sub; node < n; node += gridDim.x * NPB) {
        float4 v = ((const float4*)y)[node * C4 + c4];
        s.x += v.x; s.y += v.y; s.z += v.z; s.w += v.w;
        s2.x += v.x * v.x; s2.y += v.y * v.y; s2.z += v.z * v.z; s2.w += v.w * v.w;
    }
    __shared__ float4 ls[256], ls2[256];
    ls[threadIdx.x] = s;
    ls2[threadIdx.x] = s2;
    __syncthreads();
    if (sub == 0) {
#pragma unroll
        for (int k = 1; k < NPB; k++) {
            float4 t = ls[c4 + k * C4], t2 = ls2[c4 + k * C4];
            s.x += t.x; s.y += t.y; s.z += t.z; s.w += t.w;
            s2.x += t2.x; s2.y += t2.y; s2.z += t2.z; s2.w += t2.w;
        }
        atomicAdd(&sums[c4 * 4 + 0], s.x);
        atomicAdd(&sums[c4 * 4 + 1], s.y);
        atomicAdd(&sums[c4 * 4 + 2], s.z);
        atomicAdd(&sums[c4 * 4 + 3], s.w);
        atomicAdd(&sums[F + c4 * 4 + 0], s2.x);
        atomicAdd(&sums[F + c4 * 4 + 1], s2.y);
        atomicAdd(&sums[F + c4 * 4 + 2], s2.z);
        atomicAdd(&sums[F + c4 * 4 + 3], s2.w);
    }
}

template <int F>
__global__ void k_bn_prep(const float* __restrict__ sums, const float* __restrict__ g,
                          const float* __restrict__ be, float* __restrict__ sc,
                          float* __restrict__ sh, float invN) {
    int ch = threadIdx.x;
    if (ch < F) {
        float mean = sums[ch] * invN;
        float var = sums[F + ch] * invN - mean * mean;
        float s = g[ch] * rsqrtf(var + 1e-5f);
        sc[ch] = s;
        sh[ch] = be[ch] - mean * s;
    }
}

template <int F>
__global__ void k_bn_apply(const float* __restrict__ y, const float* __restrict__ sc,
                           const float* __restrict__ sh, float* __restrict__ outp, int n) {
    constexpr int C4 = F / 4;
    int t = blockIdx.x * blockDim.x + threadIdx.x;
    if (t >= n * C4) return;
    int node = t / C4, c4 = t % C4;
    float4 v = ((const float4*)y)[t];
    float4 o;
    o.x = v.x * sc[c4 * 4 + 0] + sh[c4 * 4 + 0];
    o.y = v.y * sc[c4 * 4 + 1] + sh[c4 * 4 + 1];
    o.z = v.z * sc[c4 * 4 + 2] + sh[c4 * 4 + 2];
    o.w = v.w * sc[c4 * 4 + 3] + sh[c4 * 4 + 3];
    ((float4*)(outp + (long long)node * 320))[c4] = o;
}

// ---------------------------------------------------------------------------
extern "C" void kernel_launch(void* const* d_in, const int* in_sizes, int n_in,
                              void* d_out, int out_size, void* d_ws, size_t ws_size,
                              hipStream_t stream) {
    const float* x   = (const float*)d_in[0];
    const int*   adj = (const int*)d_in[1];
    const float* W1  = (const float*)d_in[2];
    const float* as1 = (const float*)d_in[3];
    const float* ad1 = (const float*)d_in[4];
    const float* b1  = (const float*)d_in[5];
    const float* g1  = (const float*)d_in[6];
    const float* be1 = (const float*)d_in[7];
    const float* W2  = (const float*)d_in[8];
    const float* as2 = (const float*)d_in[9];
    const float* ad2 = (const float*)d_in[10];
    const float* b2  = (const float*)d_in[11];
    const float* g2  = (const float*)d_in[12];
    const float* be2 = (const float*)d_in[13];
    const float* W3  = (const float*)d_in[14];
    const float* as3 = (const float*)d_in[15];
    const float* ad3 = (const float*)d_in[16];
    const float* b3  = (const float*)d_in[17];
    const float* g3  = (const float*)d_in[18];
    const float* be3 = (const float*)d_in[19];
    float* out = (float*)d_out;

    const int N = in_sizes[0] / 128;
    const int E = in_sizes[1] / 2;

    // workspace
    float* ws    = (float*)d_ws;
    float* xw    = ws;                          // N*128
    float* ybuf  = xw + (size_t)N * 128;        // N*128
    float* al_s  = ybuf + (size_t)N * 128;      // N*2
    float* al_d  = al_s + (size_t)N * 2;        // N*2
    float* stats = al_d + (size_t)N * 2;        // 256
    float* scb   = stats + 256;                 // 128
    float* shb   = scb + 128;                   // 128
    int* deg       = (int*)(shb + 128);         // N
    int* row_start = deg + N;                   // N+1
    int* cursor    = row_start + (N + 1);       // N
    int* btot      = cursor + N;                // 64
    int* col       = btot + 64;                 // E+N

    const int* esrc = adj;
    const int* edst = adj + E;

    const int B = 256;
    auto cdiv = [](int a, int b) { return (a + b - 1) / b; };

    // ---- CSR build ----
    k_set1<<<cdiv(N, B), B, 0, stream>>>(deg, N);
    k_deg_count<<<cdiv(E, B), B, 0, stream>>>(edst, E, deg);
    int nsb = cdiv(N, 1024);
    k_scan1<<<nsb, 1024, 0, stream>>>(deg, row_start, btot, N);
    k_scan2<<<1, 64, 0, stream>>>(btot, nsb, row_start, N);
    k_scan3<<<nsb, 1024, 0, stream>>>(row_start, btot, N);
    k_copy_int<<<cdiv(N, B), B, 0, stream>>>(row_start, cursor, N);
    k_fill<<<cdiv(E + N, B), B, 0, stream>>>(esrc, edst, E, N, cursor, col);

    const float invN = 1.f / (float)N;

    // ---- layer 1: 128 -> 128 (H=2) ----
    k_gemm<128, false><<<cdiv(N, 64), B, 0, stream>>>(x, W1, nullptr, nullptr, xw, N);
    k_attn<128, 2><<<cdiv(N * 64, B), B, 0, stream>>>(xw, as1, ad1, al_s, al_d, N);
    k_agg<128, 2><<<cdiv(N, 4), B, 0, stream>>>(xw, al_s, al_d, row_start, col, b1, ybuf, N);
    hipMemsetAsync(stats, 0, 256 * sizeof(float), stream);
    k_bn_stats<128><<<256, B, 0, stream>>>(ybuf, stats, N);
    k_bn_prep<128><<<1, 128, 0, stream>>>(stats, g1, be1, scb, shb, invN);
    k_bn_apply<128><<<cdiv(N * 32, B), B, 0, stream>>>(ybuf, scb, shb, out + 0, N);

    // ---- layer 2: 128 -> 128 (H=2), BN(ybuf) folded into GEMM ----
    k_gemm<128, true><<<cdiv(N, 64), B, 0, stream>>>(ybuf, W2, scb, shb, xw, N);
    k_attn<128, 2><<<cdiv(N * 64, B), B, 0, stream>>>(xw, as2, ad2, al_s, al_d, N);
    k_agg<128, 2><<<cdiv(N, 4), B, 0, stream>>>(xw, al_s, al_d, row_start, col, b2, ybuf, N);
    hipMemsetAsync(stats, 0, 256 * sizeof(float), stream);
    k_bn_stats<128><<<256, B, 0, stream>>>(ybuf, stats, N);
    k_bn_prep<128><<<1, 128, 0, stream>>>(stats, g2, be2, scb, shb, invN);
    k_bn_apply<128><<<cdiv(N * 32, B), B, 0, stream>>>(ybuf, scb, shb, out + 128, N);

    // ---- layer 3: 128 -> 64 (H=1), BN(ybuf) folded into GEMM ----
    k_gemm<64, true><<<cdiv(N, 64), B, 0, stream>>>(ybuf, W3, scb, shb, xw, N);
    k_attn<64, 1><<<cdiv(N * 32, B), B, 0, stream>>>(xw, as3, ad3, al_s, al_d, N);
    k_agg<64, 1><<<cdiv(N, 4), B, 0, stream>>>(xw, al_s, al_d, row_start, col, b3, ybuf, N);
    hipMemsetAsync(stats, 0, 256 * sizeof(float), stream);
    k_bn_stats<64><<<256, B, 0, stream>>>(ybuf, stats, N);
    k_bn_prep<64><<<1, 64, 0, stream>>>(stats, g3, be3, scb, shb, invN);
    k_bn_apply<64><<<cdiv(N * 16, B), B, 0, stream>>>(ybuf, scb, shb, out + 256, N);
}

// Round 6
// 648.748 us; speedup vs baseline: 1.3666x; 1.0764x over previous
//
#include <hip/hip_runtime.h>

typedef unsigned int uint;

// ---------------------------------------------------------------------------
// GAT x3 + ReLU + BatchNorm, MI355X.
// BISECTION ROUND: exact copy of the R2-passing kernel (698us) with ONE
// change only -- k_agg phase-2 gather unrolled by 4 (unconditional shfls).
// The fused GEMM epilogue (suspected logic bug, R3-R5 absmax ~220) is OUT;
// separate k_attn restored. All-fp32 numerics (known-good: absmax 0.0625).
// ---------------------------------------------------------------------------

__global__ void k_set1(int* __restrict__ p, int n) {
    int i = blockIdx.x * blockDim.x + threadIdx.x;
    if (i < n) p[i] = 1;   // self-loop
}

__global__ void k_deg_count(const int* __restrict__ dst, int e, int* __restrict__ deg) {
    int i = blockIdx.x * blockDim.x + threadIdx.x;
    if (i < e) atomicAdd(&deg[dst[i]], 1);
}

__global__ void k_scan1(const int* __restrict__ deg, int* __restrict__ rs,
                        int* __restrict__ btot, int n) {
    __shared__ int s[1024];
    int tid = threadIdx.x;
    int i = blockIdx.x * 1024 + tid;
    int v = (i < n) ? deg[i] : 0;
    s[tid] = v;
    __syncthreads();
    for (int off = 1; off < 1024; off <<= 1) {
        int t = (tid >= off) ? s[tid - off] : 0;
        __syncthreads();
        s[tid] += t;
        __syncthreads();
    }
    if (i < n) rs[i] = s[tid] - v;
    if (tid == 1023) btot[blockIdx.x] = s[1023];
}

__global__ void k_scan2(int* __restrict__ btot, int nb, int* __restrict__ rs, int n) {
    if (threadIdx.x == 0 && blockIdx.x == 0) {
        int acc = 0;
        for (int i = 0; i < nb; i++) { int t = btot[i]; btot[i] = acc; acc += t; }
        rs[n] = acc;
    }
}

__global__ void k_scan3(int* __restrict__ rs, const int* __restrict__ btot, int n) {
    int i = blockIdx.x * 1024 + threadIdx.x;
    if (i < n) rs[i] += btot[blockIdx.x];
}

__global__ void k_copy_int(const int* __restrict__ a, int* __restrict__ b, int n) {
    int i = blockIdx.x * blockDim.x + threadIdx.x;
    if (i < n) b[i] = a[i];
}

__global__ void k_fill(const int* __restrict__ src, const int* __restrict__ dst,
                       int e, int n, int* __restrict__ cursor, int* __restrict__ col) {
    int i = blockIdx.x * blockDim.x + threadIdx.x;
    if (i < e) {
        int d = dst[i];
        int p = atomicAdd(&cursor[d], 1);
        col[p] = src[i];
    } else if (i < e + n) {
        int v = i - e;
        int p = atomicAdd(&cursor[v], 1);
        col[p] = v;
    }
}

// ---------------- GEMM: C[M,F] = BN(A)[M,128] @ W[128,F] ----------------
template <int F, bool BN>
__global__ __launch_bounds__(256) void k_gemm(const float* __restrict__ A,
                                              const float* __restrict__ W,
                                              const float* __restrict__ sc,
                                              const float* __restrict__ sh,
                                              float* __restrict__ C, int M) {
    constexpr int K = 128;
    constexpr int TN = F / 16;           // 8 (F=128) or 4 (F=64)
    __shared__ float As[32][65];
    __shared__ float Ws[32][F];
    int tid = threadIdx.x;
    int tx = tid & 15, ty = tid >> 4;
    int rowBase = blockIdx.x * 64;

    float acc[4][TN];
#pragma unroll
    for (int i = 0; i < 4; i++)
#pragma unroll
        for (int j = 0; j < TN; j++) acc[i][j] = 0.f;

    for (int k0 = 0; k0 < K; k0 += 32) {
        int c = tid & 31, rg = tid >> 5;
        float scv = BN ? sc[k0 + c] : 1.f;
        float shv = BN ? sh[k0 + c] : 0.f;
#pragma unroll
        for (int i = 0; i < 8; i++) {
            int r = rg + i * 8;
            int grow = rowBase + r;
            float a = (grow < M) ? A[(long long)grow * K + k0 + c] : 0.f;
            As[c][r] = (grow < M) ? (BN ? fmaf(a, scv, shv) : a) : 0.f;
        }
        if (F == 128) {
            int cc = tid & 127, g = tid >> 7;
#pragma unroll
            for (int j = 0; j < 16; j++) {
                int kk = g + j * 2;
                Ws[kk][cc] = W[(k0 + kk) * F + cc];
            }
        } else {
            int cc = tid & 63, g = tid >> 6;
#pragma unroll
            for (int j = 0; j < 8; j++) {
                int kk = g + j * 4;
                Ws[kk][cc] = W[(k0 + kk) * F + cc];
            }
        }
        __syncthreads();
#pragma unroll
        for (int kk = 0; kk < 32; ++kk) {
            float a0[4], w0[TN];
#pragma unroll
            for (int i = 0; i < 4; i++) a0[i] = As[kk][ty * 4 + i];
#pragma unroll
            for (int j = 0; j < TN; j++) w0[j] = Ws[kk][tx * TN + j];
#pragma unroll
            for (int i = 0; i < 4; i++)
#pragma unroll
                for (int j = 0; j < TN; j++) acc[i][j] += a0[i] * w0[j];
        }
        __syncthreads();
    }
#pragma unroll
    for (int i = 0; i < 4; i++) {
        int grow = rowBase + ty * 4 + i;
        if (grow < M) {
#pragma unroll
            for (int j = 0; j < TN; j++)
                C[(long long)grow * F + tx * TN + j] = acc[i][j];
        }
    }
}

// ---------------- attention logits: al_s/al_d [N,H], float2 loads ----------------
template <int F, int H>
__global__ void k_attn(const float* __restrict__ xw, const float* __restrict__ asrc,
                       const float* __restrict__ adst, float* __restrict__ al_s,
                       float* __restrict__ al_d, int n) {
    int t = blockIdx.x * blockDim.x + threadIdx.x;
    constexpr int C2 = F / 2;                     // float2s per node
    int node = t / C2;
    if (node >= n) return;
    int c2 = t % C2;                              // channels {2c2, 2c2+1}
    float2 x = ((const float2*)xw)[(long long)node * C2 + c2];
    float ps = x.x * asrc[2 * c2] + x.y * asrc[2 * c2 + 1];
    float pd = x.x * adst[2 * c2] + x.y * adst[2 * c2 + 1];
#pragma unroll
    for (int off = 16; off; off >>= 1) {
        ps += __shfl_xor(ps, off);
        pd += __shfl_xor(pd, off);
    }
    if ((c2 & 31) == 0) {
        int h = (2 * c2) >> 6;
        al_s[node * H + h] = ps;
        al_d[node * H + h] = pd;
    }
}

// ---------------- per-dst-wave softmax aggregation (+bias+ReLU) ----------------
template <int F, int H>
__global__ __launch_bounds__(256) void k_agg(const float* __restrict__ xw,
                      const float* __restrict__ al_s,
                      const float* __restrict__ al_d, const int* __restrict__ row_start,
                      const int* __restrict__ col, const float* __restrict__ bias,
                      float* __restrict__ y, int n) {
    int wid = (blockIdx.x * blockDim.x + threadIdx.x) >> 6;  // one wave per dst
    int lane = threadIdx.x & 63;
    if (wid >= n) return;
    int beg = row_start[wid], end = row_start[wid + 1];

    float ald[H], m[H], l[H];
#pragma unroll
    for (int h = 0; h < H; h++) {
        ald[h] = al_d[wid * H + h];
        m[h] = -1e30f;
        l[h] = 0.f;
    }
    // phase 1: online max+sum (lanes split edges)
    for (int e = beg + lane; e < end; e += 64) {
        int s = col[e];
#pragma unroll
        for (int h = 0; h < H; h++) {
            float ev = al_s[s * H + h] + ald[h];
            ev = (ev >= 0.f) ? ev : 0.2f * ev;
            if (ev > m[h]) {
                l[h] = l[h] * __expf(m[h] - ev) + 1.f;
                m[h] = ev;
            } else {
                l[h] += __expf(ev - m[h]);
            }
        }
    }
#pragma unroll
    for (int off = 32; off; off >>= 1) {
#pragma unroll
        for (int h = 0; h < H; h++) {
            float mo = __shfl_xor(m[h], off);
            float lo = __shfl_xor(l[h], off);
            float mn = fmaxf(m[h], mo);
            l[h] = l[h] * __expf(m[h] - mn) + lo * __expf(mo - mn);
            m[h] = mn;
        }
    }
    float inv[H];
#pragma unroll
    for (int h = 0; h < H; h++) inv[h] = 1.f / (l[h] + 1e-16f);

    // phase 2: lane owns channels {2*lane,2*lane+1} (F=128) or {lane} (F=64).
    // ONLY change vs passing kernel: unroll-4 with unconditional shfls.
    float acc0 = 0.f, acc1 = 0.f;
    const float2* xw2 = (const float2*)xw;
    for (int base = beg; base < end; base += 64) {
        int nb = min(64, end - base);
        int ec = min(base + lane, end - 1);
        int s = col[ec];
        float a0, a1;
        {
            float av[H];
#pragma unroll
            for (int h = 0; h < H; h++) {
                float ev = al_s[s * H + h] + ald[h];
                ev = (ev >= 0.f) ? ev : 0.2f * ev;
                av[h] = __expf(ev - m[h]) * inv[h];
            }
            a0 = av[0];
            a1 = av[H - 1];
        }
        int j = 0;
        for (; j + 4 <= nb; j += 4) {
            // unconditional shuffles (same divergence pattern as passing kernel)
            int s0 = __shfl(s, j + 0), s1 = __shfl(s, j + 1);
            int s2 = __shfl(s, j + 2), s3 = __shfl(s, j + 3);
            float q00 = __shfl(a0, j + 0), q01 = __shfl(a1, j + 0);
            float q10 = __shfl(a0, j + 1), q11 = __shfl(a1, j + 1);
            float q20 = __shfl(a0, j + 2), q21 = __shfl(a1, j + 2);
            float q30 = __shfl(a0, j + 3), q31 = __shfl(a1, j + 3);
            float p0, p1, p2, p3;
            if (H == 2) {
                p0 = (lane < 32) ? q00 : q01;
                p1 = (lane < 32) ? q10 : q11;
                p2 = (lane < 32) ? q20 : q21;
                p3 = (lane < 32) ? q30 : q31;
            } else {
                p0 = q00; p1 = q10; p2 = q20; p3 = q30;
            }
            if (F == 128) {
                float2 v0 = xw2[(s0 << 6) + lane];
                float2 v1 = xw2[(s1 << 6) + lane];
                float2 v2 = xw2[(s2 << 6) + lane];
                float2 v3 = xw2[(s3 << 6) + lane];
                acc0 = fmaf(p0, v0.x, acc0); acc1 = fmaf(p0, v0.y, acc1);
                acc0 = fmaf(p1, v1.x, acc0); acc1 = fmaf(p1, v1.y, acc1);
                acc0 = fmaf(p2, v2.x, acc0); acc1 = fmaf(p2, v2.y, acc1);
                acc0 = fmaf(p3, v3.x, acc0); acc1 = fmaf(p3, v3.y, acc1);
            } else {
                float v0 = xw[(s0 << 6) + lane];
                float v1 = xw[(s1 << 6) + lane];
                float v2 = xw[(s2 << 6) + lane];
                float v3 = xw[(s3 << 6) + lane];
                acc0 = fmaf(p0, v0, acc0);
                acc0 = fmaf(p1, v1, acc0);
                acc0 = fmaf(p2, v2, acc0);
                acc0 = fmaf(p3, v3, acc0);
            }
        }
        for (; j < nb; ++j) {
            int sj = __shfl(s, j);
            float q0 = __shfl(a0, j);
            float q1 = __shfl(a1, j);
            float alpha;
            if (H == 2) {
                alpha = (lane < 32) ? q0 : q1;
            } else {
                alpha = q0;
            }
            if (F == 128) {
                float2 v = xw2[(sj << 6) + lane];
                acc0 = fmaf(alpha, v.x, acc0);
                acc1 = fmaf(alpha, v.y, acc1);
            } else {
                float v = xw[(sj << 6) + lane];
                acc0 = fmaf(alpha, v, acc0);
            }
        }
    }
    if (F == 128) {
        float2 o;
        o.x = fmaxf(acc0 + bias[2 * lane], 0.f);
        o.y = fmaxf(acc1 + bias[2 * lane + 1], 0.f);
        ((float2*)y)[(long long)wid * 64 + lane] = o;
    } else {
        y[(long long)wid * 64 + lane] = fmaxf(acc0 + bias[lane], 0.f);
    }
}

// ---------------- BatchNorm ----------------
template <int F>
__global__ void k_bn_stats(const float* __restrict__ y, float* __restrict__ sums, int n) {
    constexpr int C4 = F / 4;
    constexpr int NPB = 256 / C4;
    int c4 = threadIdx.x % C4;
    int sub = threadIdx.x / C4;
    float4 s = {0, 0, 0, 0}, s2 = {0, 0, 0, 0};
    for (int node = blockIdx.x * NPB + sub; node < n; node += gridDim.x * NPB) {
        float4 v = ((const float4*)y)[node * C4 + c4];
        s.x += v.x; s.y += v.y; s.z += v.z; s.w += v.w;
        s2.x += v.x * v.x; s2.y += v.y * v.y; s2.z += v.z * v.z; s2.w += v.w * v.w;
    }
    __shared__ float4 ls[256], ls2[256];
    ls[threadIdx.x] = s;
    ls2[threadIdx.x] = s2;
    __syncthreads();
    if (sub == 0) {
#pragma unroll
        for (int k = 1; k < NPB; k++) {
            float4 t = ls[c4 + k * C4], t2 = ls2[c4 + k * C4];
            s.x += t.x; s.y += t.y; s.z += t.z; s.w += t.w;
            s2.x += t2.x; s2.y += t2.y; s2.z += t2.z; s2.w += t2.w;
        }
        atomicAdd(&sums[c4 * 4 + 0], s.x);
        atomicAdd(&sums[c4 * 4 + 1], s.y);
        atomicAdd(&sums[c4 * 4 + 2], s.z);
        atomicAdd(&sums[c4 * 4 + 3], s.w);
        atomicAdd(&sums[F + c4 * 4 + 0], s2.x);
        atomicAdd(&sums[F + c4 * 4 + 1], s2.y);
        atomicAdd(&sums[F + c4 * 4 + 2], s2.z);
        atomicAdd(&sums[F + c4 * 4 + 3], s2.w);
    }
}

template <int F>
__global__ void k_bn_prep(const float* __restrict__ sums, const float* __restrict__ g,
                          const float* __restrict__ be, float* __restrict__ sc,
                          float* __restrict__ sh, float invN) {
    int ch = threadIdx.x;
    if (ch < F) {
        float mean = sums[ch] * invN;
        float var = sums[F + ch] * invN - mean * mean;
        float s = g[ch] * rsqrtf(var + 1e-5f);
        sc[ch] = s;
        sh[ch] = be[ch] - mean * s;
    }
}

template <int F>
__global__ void k_bn_apply(const float* __restrict__ y, const float* __restrict__ sc,
                           const float* __restrict__ sh, float* __restrict__ outp, int n) {
    constexpr int C4 = F / 4;
    int t = blockIdx.x * blockDim.x + threadIdx.x;
    if (t >= n * C4) return;
    int node = t / C4, c4 = t % C4;
    float4 v = ((const float4*)y)[t];
    float4 o;
    o.x = v.x * sc[c4 * 4 + 0] + sh[c4 * 4 + 0];
    o.y = v.y * sc[c4 * 4 + 1] + sh[c4 * 4 + 1];
    o.z = v.z * sc[c4 * 4 + 2] + sh[c4 * 4 + 2];
    o.w = v.w * sc[c4 * 4 + 3] + sh[c4 * 4 + 3];
    ((float4*)(outp + (long long)node * 320))[c4] = o;
}

// ---------------------------------------------------------------------------
extern "C" void kernel_launch(void* const* d_in, const int* in_sizes, int n_in,
                              void* d_out, int out_size, void* d_ws, size_t ws_size,
                              hipStream_t stream) {
    const float* x   = (const float*)d_in[0];
    const int*   adj = (const int*)d_in[1];
    const float* W1  = (const float*)d_in[2];
    const float* as1 = (const float*)d_in[3];
    const float* ad1 = (const float*)d_in[4];
    const float* b1  = (const float*)d_in[5];
    const float* g1  = (const float*)d_in[6];
    const float* be1 = (const float*)d_in[7];
    const float* W2  = (const float*)d_in[8];
    const float* as2 = (const float*)d_in[9];
    const float* ad2 = (const float*)d_in[10];
    const float* b2  = (const float*)d_in[11];
    const float* g2  = (const float*)d_in[12];
    const float* be2 = (const float*)d_in[13];
    const float* W3  = (const float*)d_in[14];
    const float* as3 = (const float*)d_in[15];
    const float* ad3 = (const float*)d_in[16];
    const float* b3  = (const float*)d_in[17];
    const float* g3  = (const float*)d_in[18];
    const float* be3 = (const float*)d_in[19];
    float* out = (float*)d_out;

    const int N = in_sizes[0] / 128;
    const int E = in_sizes[1] / 2;

    // workspace
    float* ws    = (float*)d_ws;
    float* xw    = ws;                          // N*128
    float* ybuf  = xw + (size_t)N * 128;        // N*128
    float* al_s  = ybuf + (size_t)N * 128;      // N*2
    float* al_d  = al_s + (size_t)N * 2;        // N*2
    float* stats = al_d + (size_t)N * 2;        // 256
    float* scb   = stats + 256;                 // 128
    float* shb   = scb + 128;                   // 128
    int* deg       = (int*)(shb + 128);         // N
    int* row_start = deg + N;                   // N+1
    int* cursor    = row_start + (N + 1);       // N
    int* btot      = cursor + N;                // 64
    int* col       = btot + 64;                 // E+N

    const int* esrc = adj;
    const int* edst = adj + E;

    const int B = 256;
    auto cdiv = [](int a, int b) { return (a + b - 1) / b; };

    // ---- CSR build ----
    k_set1<<<cdiv(N, B), B, 0, stream>>>(deg, N);
    k_deg_count<<<cdiv(E, B), B, 0, stream>>>(edst, E, deg);
    int nsb = cdiv(N, 1024);
    k_scan1<<<nsb, 1024, 0, stream>>>(deg, row_start, btot, N);
    k_scan2<<<1, 64, 0, stream>>>(btot, nsb, row_start, N);
    k_scan3<<<nsb, 1024, 0, stream>>>(row_start, btot, N);
    k_copy_int<<<cdiv(N, B), B, 0, stream>>>(row_start, cursor, N);
    k_fill<<<cdiv(E + N, B), B, 0, stream>>>(esrc, edst, E, N, cursor, col);

    const float invN = 1.f / (float)N;

    // ---- layer 1: 128 -> 128 (H=2) ----
    k_gemm<128, false><<<cdiv(N, 64), B, 0, stream>>>(x, W1, nullptr, nullptr, xw, N);
    k_attn<128, 2><<<cdiv(N * 64, B), B, 0, stream>>>(xw, as1, ad1, al_s, al_d, N);
    k_agg<128, 2><<<cdiv(N, 4), B, 0, stream>>>(xw, al_s, al_d, row_start, col, b1, ybuf, N);
    hipMemsetAsync(stats, 0, 256 * sizeof(float), stream);
    k_bn_stats<128><<<256, B, 0, stream>>>(ybuf, stats, N);
    k_bn_prep<128><<<1, 128, 0, stream>>>(stats, g1, be1, scb, shb, invN);
    k_bn_apply<128><<<cdiv(N * 32, B), B, 0, stream>>>(ybuf, scb, shb, out + 0, N);

    // ---- layer 2: 128 -> 128 (H=2) ----
    k_gemm<128, true><<<cdiv(N, 64), B, 0, stream>>>(ybuf, W2, scb, shb, xw, N);
    k_attn<128, 2><<<cdiv(N * 64, B), B, 0, stream>>>(xw, as2, ad2, al_s, al_d, N);
    k_agg<128, 2><<<cdiv(N, 4), B, 0, stream>>>(xw, al_s, al_d, row_start, col, b2, ybuf, N);
    hipMemsetAsync(stats, 0, 256 * sizeof(float), stream);
    k_bn_stats<128><<<256, B, 0, stream>>>(ybuf, stats, N);
    k_bn_prep<128><<<1, 128, 0, stream>>>(stats, g2, be2, scb, shb, invN);
    k_bn_apply<128><<<cdiv(N * 32, B), B, 0, stream>>>(ybuf, scb, shb, out + 128, N);

    // ---- layer 3: 128 -> 64 (H=1) ----
    k_gemm<64, true><<<cdiv(N, 64), B, 0, stream>>>(ybuf, W3, scb, shb, xw, N);
    k_attn<64, 1><<<cdiv(N * 32, B), B, 0, stream>>>(xw, as3, ad3, al_s, al_d, N);
    k_agg<64, 1><<<cdiv(N, 4), B, 0, stream>>>(xw, al_s, al_d, row_start, col, b3, ybuf, N);
    hipMemsetAsync(stats, 0, 256 * sizeof(float), stream);
    k_bn_stats<64><<<256, B, 0, stream>>>(ybuf, stats, N);
    k_bn_prep<64><<<1, 64, 0, stream>>>(stats, g3, be3, scb, shb, invN);
    k_bn_apply<64><<<cdiv(N * 16, B), B, 0, stream>>>(ybuf, scb, shb, out + 256, N);
}

// Round 7
// 630.177 us; speedup vs baseline: 1.4068x; 1.0295x over previous
//
#include <hip/hip_runtime.h>

typedef unsigned int uint;

// ---------------------------------------------------------------------------
// GAT x3 + ReLU + BatchNorm, MI355X.
// R6-passing kernel (648us) + ONE experimental change: k_agg gathers bf16
// messages (packed 2/uint, produced by a separate alias-clean k_cast kernel).
// GEMM / k_attn (fp32 logits) / softmax phase-1 are byte-identical to R6.
// The R3-R5 fused-epilogue logits (proven buggy by bisection) stay dead.
// ---------------------------------------------------------------------------

static __device__ __forceinline__ uint pack_bf16x2(float lo, float hi) {
    uint a = __float_as_uint(lo);
    uint b = __float_as_uint(hi);
    a = (a + 0x7fffu + ((a >> 16) & 1u)) >> 16;   // RNE to bf16
    b = (b + 0x7fffu + ((b >> 16) & 1u)) >> 16;
    return a | (b << 16);
}

__global__ void k_set1(int* __restrict__ p, int n) {
    int i = blockIdx.x * blockDim.x + threadIdx.x;
    if (i < n) p[i] = 1;   // self-loop
}

__global__ void k_deg_count(const int* __restrict__ dst, int e, int* __restrict__ deg) {
    int i = blockIdx.x * blockDim.x + threadIdx.x;
    if (i < e) atomicAdd(&deg[dst[i]], 1);
}

__global__ void k_scan1(const int* __restrict__ deg, int* __restrict__ rs,
                        int* __restrict__ btot, int n) {
    __shared__ int s[1024];
    int tid = threadIdx.x;
    int i = blockIdx.x * 1024 + tid;
    int v = (i < n) ? deg[i] : 0;
    s[tid] = v;
    __syncthreads();
    for (int off = 1; off < 1024; off <<= 1) {
        int t = (tid >= off) ? s[tid - off] : 0;
        __syncthreads();
        s[tid] += t;
        __syncthreads();
    }
    if (i < n) rs[i] = s[tid] - v;
    if (tid == 1023) btot[blockIdx.x] = s[1023];
}

__global__ void k_scan2(int* __restrict__ btot, int nb, int* __restrict__ rs, int n) {
    if (threadIdx.x == 0 && blockIdx.x == 0) {
        int acc = 0;
        for (int i = 0; i < nb; i++) { int t = btot[i]; btot[i] = acc; acc += t; }
        rs[n] = acc;
    }
}

__global__ void k_scan3(int* __restrict__ rs, const int* __restrict__ btot, int n) {
    int i = blockIdx.x * 1024 + threadIdx.x;
    if (i < n) rs[i] += btot[blockIdx.x];
}

__global__ void k_copy_int(const int* __restrict__ a, int* __restrict__ b, int n) {
    int i = blockIdx.x * blockDim.x + threadIdx.x;
    if (i < n) b[i] = a[i];
}

__global__ void k_fill(const int* __restrict__ src, const int* __restrict__ dst,
                       int e, int n, int* __restrict__ cursor, int* __restrict__ col) {
    int i = blockIdx.x * blockDim.x + threadIdx.x;
    if (i < e) {
        int d = dst[i];
        int p = atomicAdd(&cursor[d], 1);
        col[p] = src[i];
    } else if (i < e + n) {
        int v = i - e;
        int p = atomicAdd(&cursor[v], 1);
        col[p] = v;
    }
}

// ---------------- GEMM: C[M,F] = BN(A)[M,128] @ W[128,F] (R6 verbatim) ------
template <int F, bool BN>
__global__ __launch_bounds__(256) void k_gemm(const float* __restrict__ A,
                                              const float* __restrict__ W,
                                              const float* __restrict__ sc,
                                              const float* __restrict__ sh,
                                              float* __restrict__ C, int M) {
    constexpr int K = 128;
    constexpr int TN = F / 16;           // 8 (F=128) or 4 (F=64)
    __shared__ float As[32][65];
    __shared__ float Ws[32][F];
    int tid = threadIdx.x;
    int tx = tid & 15, ty = tid >> 4;
    int rowBase = blockIdx.x * 64;

    float acc[4][TN];
#pragma unroll
    for (int i = 0; i < 4; i++)
#pragma unroll
        for (int j = 0; j < TN; j++) acc[i][j] = 0.f;

    for (int k0 = 0; k0 < K; k0 += 32) {
        int c = tid & 31, rg = tid >> 5;
        float scv = BN ? sc[k0 + c] : 1.f;
        float shv = BN ? sh[k0 + c] : 0.f;
#pragma unroll
        for (int i = 0; i < 8; i++) {
            int r = rg + i * 8;
            int grow = rowBase + r;
            float a = (grow < M) ? A[(long long)grow * K + k0 + c] : 0.f;
            As[c][r] = (grow < M) ? (BN ? fmaf(a, scv, shv) : a) : 0.f;
        }
        if (F == 128) {
            int cc = tid & 127, g = tid >> 7;
#pragma unroll
            for (int j = 0; j < 16; j++) {
                int kk = g + j * 2;
                Ws[kk][cc] = W[(k0 + kk) * F + cc];
            }
        } else {
            int cc = tid & 63, g = tid >> 6;
#pragma unroll
            for (int j = 0; j < 8; j++) {
                int kk = g + j * 4;
                Ws[kk][cc] = W[(k0 + kk) * F + cc];
            }
        }
        __syncthreads();
#pragma unroll
        for (int kk = 0; kk < 32; ++kk) {
            float a0[4], w0[TN];
#pragma unroll
            for (int i = 0; i < 4; i++) a0[i] = As[kk][ty * 4 + i];
#pragma unroll
            for (int j = 0; j < TN; j++) w0[j] = Ws[kk][tx * TN + j];
#pragma unroll
            for (int i = 0; i < 4; i++)
#pragma unroll
                for (int j = 0; j < TN; j++) acc[i][j] += a0[i] * w0[j];
        }
        __syncthreads();
    }
#pragma unroll
    for (int i = 0; i < 4; i++) {
        int grow = rowBase + ty * 4 + i;
        if (grow < M) {
#pragma unroll
            for (int j = 0; j < TN; j++)
                C[(long long)grow * F + tx * TN + j] = acc[i][j];
        }
    }
}

// ---------------- attention logits (R6 verbatim, fp32) ----------------
template <int F, int H>
__global__ void k_attn(const float* __restrict__ xw, const float* __restrict__ asrc,
                       const float* __restrict__ adst, float* __restrict__ al_s,
                       float* __restrict__ al_d, int n) {
    int t = blockIdx.x * blockDim.x + threadIdx.x;
    constexpr int C2 = F / 2;
    int node = t / C2;
    if (node >= n) return;
    int c2 = t % C2;
    float2 x = ((const float2*)xw)[(long long)node * C2 + c2];
    float ps = x.x * asrc[2 * c2] + x.y * asrc[2 * c2 + 1];
    float pd = x.x * adst[2 * c2] + x.y * adst[2 * c2 + 1];
#pragma unroll
    for (int off = 16; off; off >>= 1) {
        ps += __shfl_xor(ps, off);
        pd += __shfl_xor(pd, off);
    }
    if ((c2 & 31) == 0) {
        int h = (2 * c2) >> 6;
        al_s[node * H + h] = ps;
        al_d[node * H + h] = pd;
    }
}

// ---------------- cast: fp32 xw -> packed bf16x2 (alias-clean uints) --------
__global__ void k_cast(const float* __restrict__ xw, uint* __restrict__ xwb, int nw) {
    int i = blockIdx.x * blockDim.x + threadIdx.x;  // one uint (2 channels)
    if (i < nw) {
        float2 v = ((const float2*)xw)[i];
        xwb[i] = pack_bf16x2(v.x, v.y);
    }
}

// ---------------- per-dst-wave softmax aggregation (+bias+ReLU) ----------------
// EXPERIMENT vs R6: phase-2 gathers packed bf16 (half the bytes). Phase 1,
// alphas, shuffle pattern identical to R6-passing code.
template <int F, int H>
__global__ __launch_bounds__(256) void k_agg(const uint* __restrict__ xwb,
                      const float* __restrict__ al_s,
                      const float* __restrict__ al_d, const int* __restrict__ row_start,
                      const int* __restrict__ col, const float* __restrict__ bias,
                      float* __restrict__ y, int n) {
    int wid = (blockIdx.x * blockDim.x + threadIdx.x) >> 6;  // one wave per dst
    int lane = threadIdx.x & 63;
    if (wid >= n) return;
    int beg = row_start[wid], end = row_start[wid + 1];

    float ald[H], m[H], l[H];
#pragma unroll
    for (int h = 0; h < H; h++) {
        ald[h] = al_d[wid * H + h];
        m[h] = -1e30f;
        l[h] = 0.f;
    }
    // phase 1: online max+sum (lanes split edges) -- R6 verbatim
    for (int e = beg + lane; e < end; e += 64) {
        int s = col[e];
#pragma unroll
        for (int h = 0; h < H; h++) {
            float ev = al_s[s * H + h] + ald[h];
            ev = (ev >= 0.f) ? ev : 0.2f * ev;
            if (ev > m[h]) {
                l[h] = l[h] * __expf(m[h] - ev) + 1.f;
                m[h] = ev;
            } else {
                l[h] += __expf(ev - m[h]);
            }
        }
    }
#pragma unroll
    for (int off = 32; off; off >>= 1) {
#pragma unroll
        for (int h = 0; h < H; h++) {
            float mo = __shfl_xor(m[h], off);
            float lo = __shfl_xor(l[h], off);
            float mn = fmaxf(m[h], mo);
            l[h] = l[h] * __expf(m[h] - mn) + lo * __expf(mo - mn);
            m[h] = mn;
        }
    }
    float inv[H];
#pragma unroll
    for (int h = 0; h < H; h++) inv[h] = 1.f / (l[h] + 1e-16f);

    // phase 2: F=128: lane owns channels {2*lane,2*lane+1} = xwb[row*64+lane].
    //          F=64 : lane owns channel {lane} = half of xwb[row*32+lane/2].
    float acc0 = 0.f, acc1 = 0.f;
    for (int base = beg; base < end; base += 64) {
        int nb = min(64, end - base);
        int ec = min(base + lane, end - 1);
        int s = col[ec];
        float a0, a1;
        {
            float av[H];
#pragma unroll
            for (int h = 0; h < H; h++) {
                float ev = al_s[s * H + h] + ald[h];
                ev = (ev >= 0.f) ? ev : 0.2f * ev;
                av[h] = __expf(ev - m[h]) * inv[h];
            }
            a0 = av[0];
            a1 = av[H - 1];
        }
        int j = 0;
        for (; j + 4 <= nb; j += 4) {
            int s0 = __shfl(s, j + 0), s1 = __shfl(s, j + 1);
            int s2 = __shfl(s, j + 2), s3 = __shfl(s, j + 3);
            float q00 = __shfl(a0, j + 0), q01 = __shfl(a1, j + 0);
            float q10 = __shfl(a0, j + 1), q11 = __shfl(a1, j + 1);
            float q20 = __shfl(a0, j + 2), q21 = __shfl(a1, j + 2);
            float q30 = __shfl(a0, j + 3), q31 = __shfl(a1, j + 3);
            float p0, p1, p2, p3;
            if (H == 2) {
                p0 = (lane < 32) ? q00 : q01;
                p1 = (lane < 32) ? q10 : q11;
                p2 = (lane < 32) ? q20 : q21;
                p3 = (lane < 32) ? q30 : q31;
            } else {
                p0 = q00; p1 = q10; p2 = q20; p3 = q30;
            }
            if (F == 128) {
                uint u0 = xwb[(s0 << 6) + lane];
                uint u1 = xwb[(s1 << 6) + lane];
                uint u2 = xwb[(s2 << 6) + lane];
                uint u3 = xwb[(s3 << 6) + lane];
                acc0 = fmaf(p0, __uint_as_float(u0 << 16), acc0);
                acc1 = fmaf(p0, __uint_as_float(u0 & 0xffff0000u), acc1);
                acc0 = fmaf(p1, __uint_as_float(u1 << 16), acc0);
                acc1 = fmaf(p1, __uint_as_float(u1 & 0xffff0000u), acc1);
                acc0 = fmaf(p2, __uint_as_float(u2 << 16), acc0);
                acc1 = fmaf(p2, __uint_as_float(u2 & 0xffff0000u), acc1);
                acc0 = fmaf(p3, __uint_as_float(u3 << 16), acc0);
                acc1 = fmaf(p3, __uint_as_float(u3 & 0xffff0000u), acc1);
            } else {
                int idx = lane >> 1;
                bool hi = (lane & 1) != 0;
                uint u0 = xwb[(s0 << 5) + idx];
                uint u1 = xwb[(s1 << 5) + idx];
                uint u2 = xwb[(s2 << 5) + idx];
                uint u3 = xwb[(s3 << 5) + idx];
                acc0 = fmaf(p0, __uint_as_float(hi ? (u0 & 0xffff0000u) : (u0 << 16)), acc0);
                acc0 = fmaf(p1, __uint_as_float(hi ? (u1 & 0xffff0000u) : (u1 << 16)), acc0);
                acc0 = fmaf(p2, __uint_as_float(hi ? (u2 & 0xffff0000u) : (u2 << 16)), acc0);
                acc0 = fmaf(p3, __uint_as_float(hi ? (u3 & 0xffff0000u) : (u3 << 16)), acc0);
            }
        }
        for (; j < nb; ++j) {
            int sj = __shfl(s, j);
            float q0 = __shfl(a0, j);
            float q1 = __shfl(a1, j);
            float alpha;
            if (H == 2) {
                alpha = (lane < 32) ? q0 : q1;
            } else {
                alpha = q0;
            }
            if (F == 128) {
                uint u = xwb[(sj << 6) + lane];
                acc0 = fmaf(alpha, __uint_as_float(u << 16), acc0);
                acc1 = fmaf(alpha, __uint_as_float(u & 0xffff0000u), acc1);
            } else {
                uint u = xwb[(sj << 5) + (lane >> 1)];
                acc0 = fmaf(alpha, __uint_as_float((lane & 1) ? (u & 0xffff0000u) : (u << 16)), acc0);
            }
        }
    }
    if (F == 128) {
        float2 o;
        o.x = fmaxf(acc0 + bias[2 * lane], 0.f);
        o.y = fmaxf(acc1 + bias[2 * lane + 1], 0.f);
        ((float2*)y)[(long long)wid * 64 + lane] = o;
    } else {
        y[(long long)wid * 64 + lane] = fmaxf(acc0 + bias[lane], 0.f);
    }
}

// ---------------- BatchNorm (R6 verbatim) ----------------
template <int F>
__global__ void k_bn_stats(const float* __restrict__ y, float* __restrict__ sums, int n) {
    constexpr int C4 = F / 4;
    constexpr int NPB = 256 / C4;
    int c4 = threadIdx.x % C4;
    int sub = threadIdx.x / C4;
    float4 s = {0, 0, 0, 0}, s2 = {0, 0, 0, 0};
    for (int node = blockIdx.x * NPB + sub; node < n; node += gridDim.x * NPB) {
        float4 v = ((const float4*)y)[node * C4 + c4];
        s.x += v.x; s.y += v.y; s.z += v.z; s.w += v.w;
        s2.x += v.x * v.x; s2.y += v.y * v.y; s2.z += v.z * v.z; s2.w += v.w * v.w;
    }
    __shared__ float4 ls[256], ls2[256];
    ls[threadIdx.x] = s;
    ls2[threadIdx.x] = s2;
    __syncthreads();
    if (sub == 0) {
#pragma unroll
        for (int k = 1; k < NPB; k++) {
            float4 t = ls[c4 + k * C4], t2 = ls2[c4 + k * C4];
            s.x += t.x; s.y += t.y; s.z += t.z; s.w += t.w;
            s2.x += t2.x; s2.y += t2.y; s2.z += t2.z; s2.w += t2.w;
        }
        atomicAdd(&sums[c4 * 4 + 0], s.x);
        atomicAdd(&sums[c4 * 4 + 1], s.y);
        atomicAdd(&sums[c4 * 4 + 2], s.z);
        atomicAdd(&sums[c4 * 4 + 3], s.w);
        atomicAdd(&sums[F + c4 * 4 + 0], s2.x);
        atomicAdd(&sums[F + c4 * 4 + 1], s2.y);
        atomicAdd(&sums[F + c4 * 4 + 2], s2.z);
        atomicAdd(&sums[F + c4 * 4 + 3], s2.w);
    }
}

template <int F>
__global__ void k_bn_prep(const float* __restrict__ sums, const float* __restrict__ g,
                          const float* __restrict__ be, float* __restrict__ sc,
                          float* __restrict__ sh, float invN) {
    int ch = threadIdx.x;
    if (ch < F) {
        float mean = sums[ch] * invN;
        float var = sums[F + ch] * invN - mean * mean;
        float s = g[ch] * rsqrtf(var + 1e-5f);
        sc[ch] = s;
        sh[ch] = be[ch] - mean * s;
    }
}

template <int F>
__global__ void k_bn_apply(const float* __restrict__ y, const float* __restrict__ sc,
                           const float* __restrict__ sh, float* __restrict__ outp, int n) {
    constexpr int C4 = F / 4;
    int t = blockIdx.x * blockDim.x + threadIdx.x;
    if (t >= n * C4) return;
    int node = t / C4, c4 = t % C4;
    float4 v = ((const float4*)y)[t];
    float4 o;
    o.x = v.x * sc[c4 * 4 + 0] + sh[c4 * 4 + 0];
    o.y = v.y * sc[c4 * 4 + 1] + sh[c4 * 4 + 1];
    o.z = v.z * sc[c4 * 4 + 2] + sh[c4 * 4 + 2];
    o.w = v.w * sc[c4 * 4 + 3] + sh[c4 * 4 + 3];
    ((float4*)(outp + (long long)node * 320))[c4] = o;
}

// ---------------------------------------------------------------------------
extern "C" void kernel_launch(void* const* d_in, const int* in_sizes, int n_in,
                              void* d_out, int out_size, void* d_ws, size_t ws_size,
                              hipStream_t stream) {
    const float* x   = (const float*)d_in[0];
    const int*   adj = (const int*)d_in[1];
    const float* W1  = (const float*)d_in[2];
    const float* as1 = (const float*)d_in[3];
    const float* ad1 = (const float*)d_in[4];
    const float* b1  = (const float*)d_in[5];
    const float* g1  = (const float*)d_in[6];
    const float* be1 = (const float*)d_in[7];
    const float* W2  = (const float*)d_in[8];
    const float* as2 = (const float*)d_in[9];
    const float* ad2 = (const float*)d_in[10];
    const float* b2  = (const float*)d_in[11];
    const float* g2  = (const float*)d_in[12];
    const float* be2 = (const float*)d_in[13];
    const float* W3  = (const float*)d_in[14];
    const float* as3 = (const float*)d_in[15];
    const float* ad3 = (const float*)d_in[16];
    const float* b3  = (const float*)d_in[17];
    const float* g3  = (const float*)d_in[18];
    const float* be3 = (const float*)d_in[19];
    float* out = (float*)d_out;

    const int N = in_sizes[0] / 128;
    const int E = in_sizes[1] / 2;

    // workspace
    float* ws    = (float*)d_ws;
    float* xw    = ws;                          // N*128
    float* ybuf  = xw + (size_t)N * 128;        // N*128
    float* al_s  = ybuf + (size_t)N * 128;      // N*2
    float* al_d  = al_s + (size_t)N * 2;        // N*2
    float* stats = al_d + (size_t)N * 2;        // 256
    float* scb   = stats + 256;                 // 128
    float* shb   = scb + 128;                   // 128
    uint* xwb    = (uint*)(shb + 128);          // N*64 uints (bf16x2)
    int* deg       = (int*)(xwb + (size_t)N * 64);  // N (reused as cursor)
    int* row_start = deg + N;                   // N+1
    int* btot      = row_start + (N + 1);       // 64
    int* col       = btot + 64;                 // E+N

    const int* esrc = adj;
    const int* edst = adj + E;

    const int B = 256;
    auto cdiv = [](int a, int b) { return (a + b - 1) / b; };

    // ---- CSR build ----
    k_set1<<<cdiv(N, B), B, 0, stream>>>(deg, N);
    k_deg_count<<<cdiv(E, B), B, 0, stream>>>(edst, E, deg);
    int nsb = cdiv(N, 1024);
    k_scan1<<<nsb, 1024, 0, stream>>>(deg, row_start, btot, N);
    k_scan2<<<1, 64, 0, stream>>>(btot, nsb, row_start, N);
    k_scan3<<<nsb, 1024, 0, stream>>>(row_start, btot, N);
    k_copy_int<<<cdiv(N, B), B, 0, stream>>>(row_start, deg, N);   // deg = cursor
    k_fill<<<cdiv(E + N, B), B, 0, stream>>>(esrc, edst, E, N, deg, col);

    const float invN = 1.f / (float)N;

    // ---- layer 1: 128 -> 128 (H=2) ----
    k_gemm<128, false><<<cdiv(N, 64), B, 0, stream>>>(x, W1, nullptr, nullptr, xw, N);
    k_attn<128, 2><<<cdiv(N * 64, B), B, 0, stream>>>(xw, as1, ad1, al_s, al_d, N);
    k_cast<<<cdiv(N * 64, B), B, 0, stream>>>(xw, xwb, N * 64);
    k_agg<128, 2><<<cdiv(N, 4), B, 0, stream>>>(xwb, al_s, al_d, row_start, col, b1, ybuf, N);
    hipMemsetAsync(stats, 0, 256 * sizeof(float), stream);
    k_bn_stats<128><<<256, B, 0, stream>>>(ybuf, stats, N);
    k_bn_prep<128><<<1, 128, 0, stream>>>(stats, g1, be1, scb, shb, invN);
    k_bn_apply<128><<<cdiv(N * 32, B), B, 0, stream>>>(ybuf, scb, shb, out + 0, N);

    // ---- layer 2: 128 -> 128 (H=2) ----
    k_gemm<128, true><<<cdiv(N, 64), B, 0, stream>>>(ybuf, W2, scb, shb, xw, N);
    k_attn<128, 2><<<cdiv(N * 64, B), B, 0, stream>>>(xw, as2, ad2, al_s, al_d, N);
    k_cast<<<cdiv(N * 64, B), B, 0, stream>>>(xw, xwb, N * 64);
    k_agg<128, 2><<<cdiv(N, 4), B, 0, stream>>>(xwb, al_s, al_d, row_start, col, b2, ybuf, N);
    hipMemsetAsync(stats, 0, 256 * sizeof(float), stream);
    k_bn_stats<128><<<256, B, 0, stream>>>(ybuf, stats, N);
    k_bn_prep<128><<<1, 128, 0, stream>>>(stats, g2, be2, scb, shb, invN);
    k_bn_apply<128><<<cdiv(N * 32, B), B, 0, stream>>>(ybuf, scb, shb, out + 128, N);

    // ---- layer 3: 128 -> 64 (H=1) ----
    k_gemm<64, true><<<cdiv(N, 64), B, 0, stream>>>(ybuf, W3, scb, shb, xw, N);
    k_attn<64, 1><<<cdiv(N * 32, B), B, 0, stream>>>(xw, as3, ad3, al_s, al_d, N);
    k_cast<<<cdiv(N * 32, B), B, 0, stream>>>(xw, xwb, N * 32);
    k_agg<64, 1><<<cdiv(N, 4), B, 0, stream>>>(xwb, al_s, al_d, row_start, col, b3, ybuf, N);
    hipMemsetAsync(stats, 0, 256 * sizeof(float), stream);
    k_bn_stats<64><<<256, B, 0, stream>>>(ybuf, stats, N);
    k_bn_prep<64><<<1, 64, 0, stream>>>(stats, g3, be3, scb, shb, invN);
    k_bn_apply<64><<<cdiv(N * 16, B), B, 0, stream>>>(ybuf, scb, shb, out + 256, N);
}

// Round 8
// 600.198 us; speedup vs baseline: 1.4771x; 1.0499x over previous
//
#include <hip/hip_runtime.h>

typedef unsigned int uint;
typedef unsigned short ushort;

// ---------------------------------------------------------------------------
// GAT x3 + ReLU + BatchNorm, MI355X.
// R7-passing pipeline (630us). ONE change: k_gemm -> MFMA split-bf16
// (a_hi*b_hi + a_hi*b_lo + a_lo*b_hi, fp32 accum, ~1e-4 rel err).
// k_attn / k_cast / k_agg (bf16 gather) / BN / CSR are R7-verbatim.
// ---------------------------------------------------------------------------

static __device__ __forceinline__ uint pack_bf16x2(float lo, float hi) {
    uint a = __float_as_uint(lo);
    uint b = __float_as_uint(hi);
    a = (a + 0x7fffu + ((a >> 16) & 1u)) >> 16;   // RNE to bf16
    b = (b + 0x7fffu + ((b >> 16) & 1u)) >> 16;
    return a | (b << 16);
}

static __device__ __forceinline__ ushort bf16_rne(float x) {
    uint u = __float_as_uint(x);
    return (ushort)((u + 0x7fffu + ((u >> 16) & 1u)) >> 16);
}
static __device__ __forceinline__ float bf16_f(ushort h) {
    return __uint_as_float(((uint)h) << 16);
}

__global__ void k_set1(int* __restrict__ p, int n) {
    int i = blockIdx.x * blockDim.x + threadIdx.x;
    if (i < n) p[i] = 1;   // self-loop
}

__global__ void k_deg_count(const int* __restrict__ dst, int e, int* __restrict__ deg) {
    int i = blockIdx.x * blockDim.x + threadIdx.x;
    if (i < e) atomicAdd(&deg[dst[i]], 1);
}

__global__ void k_scan1(const int* __restrict__ deg, int* __restrict__ rs,
                        int* __restrict__ btot, int n) {
    __shared__ int s[1024];
    int tid = threadIdx.x;
    int i = blockIdx.x * 1024 + tid;
    int v = (i < n) ? deg[i] : 0;
    s[tid] = v;
    __syncthreads();
    for (int off = 1; off < 1024; off <<= 1) {
        int t = (tid >= off) ? s[tid - off] : 0;
        __syncthreads();
        s[tid] += t;
        __syncthreads();
    }
    if (i < n) rs[i] = s[tid] - v;
    if (tid == 1023) btot[blockIdx.x] = s[1023];
}

__global__ void k_scan2(int* __restrict__ btot, int nb, int* __restrict__ rs, int n) {
    if (threadIdx.x == 0 && blockIdx.x == 0) {
        int acc = 0;
        for (int i = 0; i < nb; i++) { int t = btot[i]; btot[i] = acc; acc += t; }
        rs[n] = acc;
    }
}

__global__ void k_scan3(int* __restrict__ rs, const int* __restrict__ btot, int n) {
    int i = blockIdx.x * 1024 + threadIdx.x;
    if (i < n) rs[i] += btot[blockIdx.x];
}

__global__ void k_copy_int(const int* __restrict__ a, int* __restrict__ b, int n) {
    int i = blockIdx.x * blockDim.x + threadIdx.x;
    if (i < n) b[i] = a[i];
}

__global__ void k_fill(const int* __restrict__ src, const int* __restrict__ dst,
                       int e, int n, int* __restrict__ cursor, int* __restrict__ col) {
    int i = blockIdx.x * blockDim.x + threadIdx.x;
    if (i < e) {
        int d = dst[i];
        int p = atomicAdd(&cursor[d], 1);
        col[p] = src[i];
    } else if (i < e + n) {
        int v = i - e;
        int p = atomicAdd(&cursor[v], 1);
        col[p] = v;
    }
}

// ---------------- GEMM: xw[M,F] = BN(A)[M,128] @ W[128,F], MFMA split-bf16 ----
typedef __attribute__((ext_vector_type(8))) short short8;
typedef __attribute__((ext_vector_type(4))) float float4v;

template <int F, bool BN>
__global__ __launch_bounds__(256) void k_gemm(const float* __restrict__ A,
                                              const float* __restrict__ W,
                                              const float* __restrict__ sc,
                                              const float* __restrict__ sh,
                                              float* __restrict__ xw, int M) {
    constexpr int K = 128;
    constexpr int NT = F / 16;              // 8 (F=128) or 4 (F=64) n-tiles
    // stride 40 ushorts = 80 B: 16B-aligned rows, ~2-way LDS bank alias (free)
    __shared__ __align__(16) ushort Ahi[64][40], Alo[64][40];
    __shared__ __align__(16) ushort Whi[F][40], Wlo[F][40];
    int tid = threadIdx.x;
    int wave = tid >> 6, lane = tid & 63;
    int quad = lane >> 4, l15 = lane & 15;
    int rowBase = blockIdx.x * 64;

    float4v acc[NT];
#pragma unroll
    for (int t = 0; t < NT; t++) acc[t] = (float4v){0.f, 0.f, 0.f, 0.f};

    for (int k0 = 0; k0 < K; k0 += 32) {
        // ---- stage A tile: 64 rows x 32 k (8 elems/thread), BN folded ----
        {
            int kk = tid & 31, rg = tid >> 5;
            float scv = BN ? sc[k0 + kk] : 1.f;
            float shv = BN ? sh[k0 + kk] : 0.f;
#pragma unroll
            for (int i = 0; i < 8; i++) {
                int r = rg + i * 8;
                int grow = rowBase + r;
                float a = (grow < M) ? A[(long long)grow * K + k0 + kk] : 0.f;
                if (BN) a = fmaf(a, scv, shv);
                ushort hi = bf16_rne(a);
                ushort lo = bf16_rne(a - bf16_f(hi));
                Ahi[r][kk] = hi;
                Alo[r][kk] = lo;
            }
        }
        // ---- stage W tile: 32 k x F, transposed to [n][k] ----
        if (F == 128) {
            int n = tid & 127, kg = tid >> 7;        // kg in {0,1}
#pragma unroll
            for (int j = 0; j < 16; j++) {
                int kk = kg + j * 2;
                float w = W[(long long)(k0 + kk) * F + n];
                ushort hi = bf16_rne(w);
                ushort lo = bf16_rne(w - bf16_f(hi));
                Whi[n][kk] = hi;
                Wlo[n][kk] = lo;
            }
        } else {
            int n = tid & 63, kg = tid >> 6;         // kg in {0..3}
#pragma unroll
            for (int j = 0; j < 8; j++) {
                int kk = kg + j * 4;
                float w = W[(long long)(k0 + kk) * F + n];
                ushort hi = bf16_rne(w);
                ushort lo = bf16_rne(w - bf16_f(hi));
                Whi[n][kk] = hi;
                Wlo[n][kk] = lo;
            }
        }
        __syncthreads();

        // ---- MFMA: each wave covers rows wave*16..+15, all NT col-tiles ----
        // A frag: A[m=lane&15][k=quad*8+j]; B frag: W[k=quad*8+j][n=lane&15]
        short8 ah = *(const short8*)&Ahi[wave * 16 + l15][quad * 8];
        short8 al = *(const short8*)&Alo[wave * 16 + l15][quad * 8];
#pragma unroll
        for (int t = 0; t < NT; t++) {
            short8 bh = *(const short8*)&Whi[t * 16 + l15][quad * 8];
            short8 bl = *(const short8*)&Wlo[t * 16 + l15][quad * 8];
            acc[t] = __builtin_amdgcn_mfma_f32_16x16x32_bf16(ah, bh, acc[t], 0, 0, 0);
            acc[t] = __builtin_amdgcn_mfma_f32_16x16x32_bf16(ah, bl, acc[t], 0, 0, 0);
            acc[t] = __builtin_amdgcn_mfma_f32_16x16x32_bf16(al, bh, acc[t], 0, 0, 0);
        }
        __syncthreads();
    }

    // ---- epilogue: C/D layout row=quad*4+reg, col=lane&15 ----
#pragma unroll
    for (int r = 0; r < 4; r++) {
        int grow = rowBase + wave * 16 + quad * 4 + r;
        if (grow < M) {
#pragma unroll
            for (int t = 0; t < NT; t++)
                xw[(long long)grow * F + t * 16 + l15] = acc[t][r];
        }
    }
}

// ---------------- attention logits (fp32, R7 verbatim) ----------------
template <int F, int H>
__global__ void k_attn(const float* __restrict__ xw, const float* __restrict__ asrc,
                       const float* __restrict__ adst, float* __restrict__ al_s,
                       float* __restrict__ al_d, int n) {
    int t = blockIdx.x * blockDim.x + threadIdx.x;
    constexpr int C2 = F / 2;
    int node = t / C2;
    if (node >= n) return;
    int c2 = t % C2;
    float2 x = ((const float2*)xw)[(long long)node * C2 + c2];
    float ps = x.x * asrc[2 * c2] + x.y * asrc[2 * c2 + 1];
    float pd = x.x * adst[2 * c2] + x.y * adst[2 * c2 + 1];
#pragma unroll
    for (int off = 16; off; off >>= 1) {
        ps += __shfl_xor(ps, off);
        pd += __shfl_xor(pd, off);
    }
    if ((c2 & 31) == 0) {
        int h = (2 * c2) >> 6;
        al_s[node * H + h] = ps;
        al_d[node * H + h] = pd;
    }
}

// ---------------- cast: fp32 xw -> packed bf16x2 (R7 verbatim) --------------
__global__ void k_cast(const float* __restrict__ xw, uint* __restrict__ xwb, int nw) {
    int i = blockIdx.x * blockDim.x + threadIdx.x;
    if (i < nw) {
        float2 v = ((const float2*)xw)[i];
        xwb[i] = pack_bf16x2(v.x, v.y);
    }
}

// ---------------- per-dst-wave softmax aggregation (R7 verbatim) ------------
template <int F, int H>
__global__ __launch_bounds__(256) void k_agg(const uint* __restrict__ xwb,
                      const float* __restrict__ al_s,
                      const float* __restrict__ al_d, const int* __restrict__ row_start,
                      const int* __restrict__ col, const float* __restrict__ bias,
                      float* __restrict__ y, int n) {
    int wid = (blockIdx.x * blockDim.x + threadIdx.x) >> 6;  // one wave per dst
    int lane = threadIdx.x & 63;
    if (wid >= n) return;
    int beg = row_start[wid], end = row_start[wid + 1];

    float ald[H], m[H], l[H];
#pragma unroll
    for (int h = 0; h < H; h++) {
        ald[h] = al_d[wid * H + h];
        m[h] = -1e30f;
        l[h] = 0.f;
    }
    for (int e = beg + lane; e < end; e += 64) {
        int s = col[e];
#pragma unroll
        for (int h = 0; h < H; h++) {
            float ev = al_s[s * H + h] + ald[h];
            ev = (ev >= 0.f) ? ev : 0.2f * ev;
            if (ev > m[h]) {
                l[h] = l[h] * __expf(m[h] - ev) + 1.f;
                m[h] = ev;
            } else {
                l[h] += __expf(ev - m[h]);
            }
        }
    }
#pragma unroll
    for (int off = 32; off; off >>= 1) {
#pragma unroll
        for (int h = 0; h < H; h++) {
            float mo = __shfl_xor(m[h], off);
            float lo = __shfl_xor(l[h], off);
            float mn = fmaxf(m[h], mo);
            l[h] = l[h] * __expf(m[h] - mn) + lo * __expf(mo - mn);
            m[h] = mn;
        }
    }
    float inv[H];
#pragma unroll
    for (int h = 0; h < H; h++) inv[h] = 1.f / (l[h] + 1e-16f);

    float acc0 = 0.f, acc1 = 0.f;
    for (int base = beg; base < end; base += 64) {
        int nb = min(64, end - base);
        int ec = min(base + lane, end - 1);
        int s = col[ec];
        float a0, a1;
        {
            float av[H];
#pragma unroll
            for (int h = 0; h < H; h++) {
                float ev = al_s[s * H + h] + ald[h];
                ev = (ev >= 0.f) ? ev : 0.2f * ev;
                av[h] = __expf(ev - m[h]) * inv[h];
            }
            a0 = av[0];
            a1 = av[H - 1];
        }
        int j = 0;
        for (; j + 4 <= nb; j += 4) {
            int s0 = __shfl(s, j + 0), s1 = __shfl(s, j + 1);
            int s2 = __shfl(s, j + 2), s3 = __shfl(s, j + 3);
            float q00 = __shfl(a0, j + 0), q01 = __shfl(a1, j + 0);
            float q10 = __shfl(a0, j + 1), q11 = __shfl(a1, j + 1);
            float q20 = __shfl(a0, j + 2), q21 = __shfl(a1, j + 2);
            float q30 = __shfl(a0, j + 3), q31 = __shfl(a1, j + 3);
            float p0, p1, p2, p3;
            if (H == 2) {
                p0 = (lane < 32) ? q00 : q01;
                p1 = (lane < 32) ? q10 : q11;
                p2 = (lane < 32) ? q20 : q21;
                p3 = (lane < 32) ? q30 : q31;
            } else {
                p0 = q00; p1 = q10; p2 = q20; p3 = q30;
            }
            if (F == 128) {
                uint u0 = xwb[(s0 << 6) + lane];
                uint u1 = xwb[(s1 << 6) + lane];
                uint u2 = xwb[(s2 << 6) + lane];
                uint u3 = xwb[(s3 << 6) + lane];
                acc0 = fmaf(p0, __uint_as_float(u0 << 16), acc0);
                acc1 = fmaf(p0, __uint_as_float(u0 & 0xffff0000u), acc1);
                acc0 = fmaf(p1, __uint_as_float(u1 << 16), acc0);
                acc1 = fmaf(p1, __uint_as_float(u1 & 0xffff0000u), acc1);
                acc0 = fmaf(p2, __uint_as_float(u2 << 16), acc0);
                acc1 = fmaf(p2, __uint_as_float(u2 & 0xffff0000u), acc1);
                acc0 = fmaf(p3, __uint_as_float(u3 << 16), acc0);
                acc1 = fmaf(p3, __uint_as_float(u3 & 0xffff0000u), acc1);
            } else {
                int idx = lane >> 1;
                bool hi = (lane & 1) != 0;
                uint u0 = xwb[(s0 << 5) + idx];
                uint u1 = xwb[(s1 << 5) + idx];
                uint u2 = xwb[(s2 << 5) + idx];
                uint u3 = xwb[(s3 << 5) + idx];
                acc0 = fmaf(p0, __uint_as_float(hi ? (u0 & 0xffff0000u) : (u0 << 16)), acc0);
                acc0 = fmaf(p1, __uint_as_float(hi ? (u1 & 0xffff0000u) : (u1 << 16)), acc0);
                acc0 = fmaf(p2, __uint_as_float(hi ? (u2 & 0xffff0000u) : (u2 << 16)), acc0);
                acc0 = fmaf(p3, __uint_as_float(hi ? (u3 & 0xffff0000u) : (u3 << 16)), acc0);
            }
        }
        for (; j < nb; ++j) {
            int sj = __shfl(s, j);
            float q0 = __shfl(a0, j);
            float q1 = __shfl(a1, j);
            float alpha;
            if (H == 2) {
                alpha = (lane < 32) ? q0 : q1;
            } else {
                alpha = q0;
            }
            if (F == 128) {
                uint u = xwb[(sj << 6) + lane];
                acc0 = fmaf(alpha, __uint_as_float(u << 16), acc0);
                acc1 = fmaf(alpha, __uint_as_float(u & 0xffff0000u), acc1);
            } else {
                uint u = xwb[(sj << 5) + (lane >> 1)];
                acc0 = fmaf(alpha, __uint_as_float((lane & 1) ? (u & 0xffff0000u) : (u << 16)), acc0);
            }
        }
    }
    if (F == 128) {
        float2 o;
        o.x = fmaxf(acc0 + bias[2 * lane], 0.f);
        o.y = fmaxf(acc1 + bias[2 * lane + 1], 0.f);
        ((float2*)y)[(long long)wid * 64 + lane] = o;
    } else {
        y[(long long)wid * 64 + lane] = fmaxf(acc0 + bias[lane], 0.f);
    }
}

// ---------------- BatchNorm (R7 verbatim) ----------------
template <int F>
__global__ void k_bn_stats(const float* __restrict__ y, float* __restrict__ sums, int n) {
    constexpr int C4 = F / 4;
    constexpr int NPB = 256 / C4;
    int c4 = threadIdx.x % C4;
    int sub = threadIdx.x / C4;
    float4 s = {0, 0, 0, 0}, s2 = {0, 0, 0, 0};
    for (int node = blockIdx.x * NPB + sub; node < n; node += gridDim.x * NPB) {
        float4 v = ((const float4*)y)[node * C4 + c4];
        s.x += v.x; s.y += v.y; s.z += v.z; s.w += v.w;
        s2.x += v.x * v.x; s2.y += v.y * v.y; s2.z += v.z * v.z; s2.w += v.w * v.w;
    }
    __shared__ float4 ls[256], ls2[256];
    ls[threadIdx.x] = s;
    ls2[threadIdx.x] = s2;
    __syncthreads();
    if (sub == 0) {
#pragma unroll
        for (int k = 1; k < NPB; k++) {
            float4 t = ls[c4 + k * C4], t2 = ls2[c4 + k * C4];
            s.x += t.x; s.y += t.y; s.z += t.z; s.w += t.w;
            s2.x += t2.x; s2.y += t2.y; s2.z += t2.z; s2.w += t2.w;
        }
        atomicAdd(&sums[c4 * 4 + 0], s.x);
        atomicAdd(&sums[c4 * 4 + 1], s.y);
        atomicAdd(&sums[c4 * 4 + 2], s.z);
        atomicAdd(&sums[c4 * 4 + 3], s.w);
        atomicAdd(&sums[F + c4 * 4 + 0], s2.x);
        atomicAdd(&sums[F + c4 * 4 + 1], s2.y);
        atomicAdd(&sums[F + c4 * 4 + 2], s2.z);
        atomicAdd(&sums[F + c4 * 4 + 3], s2.w);
    }
}

template <int F>
__global__ void k_bn_prep(const float* __restrict__ sums, const float* __restrict__ g,
                          const float* __restrict__ be, float* __restrict__ sc,
                          float* __restrict__ sh, float invN) {
    int ch = threadIdx.x;
    if (ch < F) {
        float mean = sums[ch] * invN;
        float var = sums[F + ch] * invN - mean * mean;
        float s = g[ch] * rsqrtf(var + 1e-5f);
        sc[ch] = s;
        sh[ch] = be[ch] - mean * s;
    }
}

template <int F>
__global__ void k_bn_apply(const float* __restrict__ y, const float* __restrict__ sc,
                           const float* __restrict__ sh, float* __restrict__ outp, int n) {
    constexpr int C4 = F / 4;
    int t = blockIdx.x * blockDim.x + threadIdx.x;
    if (t >= n * C4) return;
    int node = t / C4, c4 = t % C4;
    float4 v = ((const float4*)y)[t];
    float4 o;
    o.x = v.x * sc[c4 * 4 + 0] + sh[c4 * 4 + 0];
    o.y = v.y * sc[c4 * 4 + 1] + sh[c4 * 4 + 1];
    o.z = v.z * sc[c4 * 4 + 2] + sh[c4 * 4 + 2];
    o.w = v.w * sc[c4 * 4 + 3] + sh[c4 * 4 + 3];
    ((float4*)(outp + (long long)node * 320))[c4] = o;
}

// ---------------------------------------------------------------------------
extern "C" void kernel_launch(void* const* d_in, const int* in_sizes, int n_in,
                              void* d_out, int out_size, void* d_ws, size_t ws_size,
                              hipStream_t stream) {
    const float* x   = (const float*)d_in[0];
    const int*   adj = (const int*)d_in[1];
    const float* W1  = (const float*)d_in[2];
    const float* as1 = (const float*)d_in[3];
    const float* ad1 = (const float*)d_in[4];
    const float* b1  = (const float*)d_in[5];
    const float* g1  = (const float*)d_in[6];
    const float* be1 = (const float*)d_in[7];
    const float* W2  = (const float*)d_in[8];
    const float* as2 = (const float*)d_in[9];
    const float* ad2 = (const float*)d_in[10];
    const float* b2  = (const float*)d_in[11];
    const float* g2  = (const float*)d_in[12];
    const float* be2 = (const float*)d_in[13];
    const float* W3  = (const float*)d_in[14];
    const float* as3 = (const float*)d_in[15];
    const float* ad3 = (const float*)d_in[16];
    const float* b3  = (const float*)d_in[17];
    const float* g3  = (const float*)d_in[18];
    const float* be3 = (const float*)d_in[19];
    float* out = (float*)d_out;

    const int N = in_sizes[0] / 128;
    const int E = in_sizes[1] / 2;

    // workspace
    float* ws    = (float*)d_ws;
    float* xw    = ws;                          // N*128
    float* ybuf  = xw + (size_t)N * 128;        // N*128
    float* al_s  = ybuf + (size_t)N * 128;      // N*2
    float* al_d  = al_s + (size_t)N * 2;        // N*2
    float* stats = al_d + (size_t)N * 2;        // 256
    float* scb   = stats + 256;                 // 128
    float* shb   = scb + 128;                   // 128
    uint* xwb    = (uint*)(shb + 128);          // N*64 uints (bf16x2)
    int* deg       = (int*)(xwb + (size_t)N * 64);  // N (reused as cursor)
    int* row_start = deg + N;                   // N+1
    int* btot      = row_start + (N + 1);       // 64
    int* col       = btot + 64;                 // E+N

    const int* esrc = adj;
    const int* edst = adj + E;

    const int B = 256;
    auto cdiv = [](int a, int b) { return (a + b - 1) / b; };

    // ---- CSR build ----
    k_set1<<<cdiv(N, B), B, 0, stream>>>(deg, N);
    k_deg_count<<<cdiv(E, B), B, 0, stream>>>(edst, E, deg);
    int nsb = cdiv(N, 1024);
    k_scan1<<<nsb, 1024, 0, stream>>>(deg, row_start, btot, N);
    k_scan2<<<1, 64, 0, stream>>>(btot, nsb, row_start, N);
    k_scan3<<<nsb, 1024, 0, stream>>>(row_start, btot, N);
    k_copy_int<<<cdiv(N, B), B, 0, stream>>>(row_start, deg, N);   // deg = cursor
    k_fill<<<cdiv(E + N, B), B, 0, stream>>>(esrc, edst, E, N, deg, col);

    const float invN = 1.f / (float)N;

    // ---- layer 1: 128 -> 128 (H=2) ----
    k_gemm<128, false><<<cdiv(N, 64), B, 0, stream>>>(x, W1, nullptr, nullptr, xw, N);
    k_attn<128, 2><<<cdiv(N * 64, B), B, 0, stream>>>(xw, as1, ad1, al_s, al_d, N);
    k_cast<<<cdiv(N * 64, B), B, 0, stream>>>(xw, xwb, N * 64);
    k_agg<128, 2><<<cdiv(N, 4), B, 0, stream>>>(xwb, al_s, al_d, row_start, col, b1, ybuf, N);
    hipMemsetAsync(stats, 0, 256 * sizeof(float), stream);
    k_bn_stats<128><<<256, B, 0, stream>>>(ybuf, stats, N);
    k_bn_prep<128><<<1, 128, 0, stream>>>(stats, g1, be1, scb, shb, invN);
    k_bn_apply<128><<<cdiv(N * 32, B), B, 0, stream>>>(ybuf, scb, shb, out + 0, N);

    // ---- layer 2: 128 -> 128 (H=2) ----
    k_gemm<128, true><<<cdiv(N, 64), B, 0, stream>>>(ybuf, W2, scb, shb, xw, N);
    k_attn<128, 2><<<cdiv(N * 64, B), B, 0, stream>>>(xw, as2, ad2, al_s, al_d, N);
    k_cast<<<cdiv(N * 64, B), B, 0, stream>>>(xw, xwb, N * 64);
    k_agg<128, 2><<<cdiv(N, 4), B, 0, stream>>>(xwb, al_s, al_d, row_start, col, b2, ybuf, N);
    hipMemsetAsync(stats, 0, 256 * sizeof(float), stream);
    k_bn_stats<128><<<256, B, 0, stream>>>(ybuf, stats, N);
    k_bn_prep<128><<<1, 128, 0, stream>>>(stats, g2, be2, scb, shb, invN);
    k_bn_apply<128><<<cdiv(N * 32, B), B, 0, stream>>>(ybuf, scb, shb, out + 128, N);

    // ---- layer 3: 128 -> 64 (H=1) ----
    k_gemm<64, true><<<cdiv(N, 64), B, 0, stream>>>(ybuf, W3, scb, shb, xw, N);
    k_attn<64, 1><<<cdiv(N * 32, B), B, 0, stream>>>(xw, as3, ad3, al_s, al_d, N);
    k_cast<<<cdiv(N * 32, B), B, 0, stream>>>(xw, xwb, N * 32);
    k_agg<64, 1><<<cdiv(N, 4), B, 0, stream>>>(xwb, al_s, al_d, row_start, col, b3, ybuf, N);
    hipMemsetAsync(stats, 0, 256 * sizeof(float), stream);
    k_bn_stats<64><<<256, B, 0, stream>>>(ybuf, stats, N);
    k_bn_prep<64><<<1, 64, 0, stream>>>(stats, g3, be3, scb, shb, invN);
    k_bn_apply<64><<<cdiv(N * 16, B), B, 0, stream>>>(ybuf, scb, shb, out + 256, N);
}

// Round 9
// 579.490 us; speedup vs baseline: 1.5299x; 1.0357x over previous
//
#include <hip/hip_runtime.h>

typedef unsigned int uint;
typedef unsigned short ushort;

// ---------------------------------------------------------------------------
// GAT x3 + ReLU + BatchNorm, MI355X.
// R8-passing pipeline (600us) + two independent-kernel changes:
//  1) k_fill: non-temporal 4B scatter stores (cut 64B-line writeback ampl.)
//  2) MFMA k_gemm epilogue now emits bf16 xwb + attention logits directly
//     (k_attn, k_cast, and the fp32 xw buffer are gone). Logit reduction
//     uses the verified MFMA C layout: C[row=quad*4+r][col=t*16+l15],
//     16-lane butterfly within the quad group.
// k_agg / BN / CSR are R8-verbatim.
// ---------------------------------------------------------------------------

static __device__ __forceinline__ ushort bf16_rne(float x) {
    uint u = __float_as_uint(x);
    return (ushort)((u + 0x7fffu + ((u >> 16) & 1u)) >> 16);
}
static __device__ __forceinline__ float bf16_f(ushort h) {
    return __uint_as_float(((uint)h) << 16);
}

__global__ void k_set1(int* __restrict__ p, int n) {
    int i = blockIdx.x * blockDim.x + threadIdx.x;
    if (i < n) p[i] = 1;   // self-loop
}

__global__ void k_deg_count(const int* __restrict__ dst, int e, int* __restrict__ deg) {
    int i = blockIdx.x * blockDim.x + threadIdx.x;
    if (i < e) atomicAdd(&deg[dst[i]], 1);
}

__global__ void k_scan1(const int* __restrict__ deg, int* __restrict__ rs,
                        int* __restrict__ btot, int n) {
    __shared__ int s[1024];
    int tid = threadIdx.x;
    int i = blockIdx.x * 1024 + tid;
    int v = (i < n) ? deg[i] : 0;
    s[tid] = v;
    __syncthreads();
    for (int off = 1; off < 1024; off <<= 1) {
        int t = (tid >= off) ? s[tid - off] : 0;
        __syncthreads();
        s[tid] += t;
        __syncthreads();
    }
    if (i < n) rs[i] = s[tid] - v;
    if (tid == 1023) btot[blockIdx.x] = s[1023];
}

__global__ void k_scan2(int* __restrict__ btot, int nb, int* __restrict__ rs, int n) {
    if (threadIdx.x == 0 && blockIdx.x == 0) {
        int acc = 0;
        for (int i = 0; i < nb; i++) { int t = btot[i]; btot[i] = acc; acc += t; }
        rs[n] = acc;
    }
}

__global__ void k_scan3(int* __restrict__ rs, const int* __restrict__ btot, int n) {
    int i = blockIdx.x * 1024 + threadIdx.x;
    if (i < n) rs[i] += btot[blockIdx.x];
}

__global__ void k_copy_int(const int* __restrict__ a, int* __restrict__ b, int n) {
    int i = blockIdx.x * blockDim.x + threadIdx.x;
    if (i < n) b[i] = a[i];
}

__global__ void k_fill(const int* __restrict__ src, const int* __restrict__ dst,
                       int e, int n, int* __restrict__ cursor, int* __restrict__ col) {
    int i = blockIdx.x * blockDim.x + threadIdx.x;
    if (i < e) {
        int d = dst[i];
        int p = atomicAdd(&cursor[d], 1);
        __builtin_nontemporal_store(src[i], &col[p]);
    } else if (i < e + n) {
        int v = i - e;
        int p = atomicAdd(&cursor[v], 1);
        __builtin_nontemporal_store(v, &col[p]);
    }
}

// ---- GEMM: BN(A)[M,128] @ W[128,F] -> bf16 xwb + logits (MFMA split-bf16) ---
typedef __attribute__((ext_vector_type(8))) short short8;
typedef __attribute__((ext_vector_type(4))) float float4v;

template <int F, int H, bool BN>
__global__ __launch_bounds__(256) void k_gemm(const float* __restrict__ A,
                                              const float* __restrict__ W,
                                              const float* __restrict__ sc,
                                              const float* __restrict__ sh,
                                              const float* __restrict__ asrc,
                                              const float* __restrict__ adst,
                                              ushort* __restrict__ xwb,
                                              float* __restrict__ al_s,
                                              float* __restrict__ al_d, int M) {
    constexpr int K = 128;
    constexpr int NT = F / 16;              // 8 (F=128) or 4 (F=64) n-tiles
    __shared__ __align__(16) ushort Ahi[64][40], Alo[64][40];
    __shared__ __align__(16) ushort Whi[F][40], Wlo[F][40];
    int tid = threadIdx.x;
    int wave = tid >> 6, lane = tid & 63;
    int quad = lane >> 4, l15 = lane & 15;
    int rowBase = blockIdx.x * 64;

    float4v acc[NT];
#pragma unroll
    for (int t = 0; t < NT; t++) acc[t] = (float4v){0.f, 0.f, 0.f, 0.f};

    for (int k0 = 0; k0 < K; k0 += 32) {
        {
            int kk = tid & 31, rg = tid >> 5;
            float scv = BN ? sc[k0 + kk] : 1.f;
            float shv = BN ? sh[k0 + kk] : 0.f;
#pragma unroll
            for (int i = 0; i < 8; i++) {
                int r = rg + i * 8;
                int grow = rowBase + r;
                float a = (grow < M) ? A[(long long)grow * K + k0 + kk] : 0.f;
                if (BN) a = fmaf(a, scv, shv);
                ushort hi = bf16_rne(a);
                ushort lo = bf16_rne(a - bf16_f(hi));
                Ahi[r][kk] = hi;
                Alo[r][kk] = lo;
            }
        }
        if (F == 128) {
            int n = tid & 127, kg = tid >> 7;
#pragma unroll
            for (int j = 0; j < 16; j++) {
                int kk = kg + j * 2;
                float w = W[(long long)(k0 + kk) * F + n];
                ushort hi = bf16_rne(w);
                ushort lo = bf16_rne(w - bf16_f(hi));
                Whi[n][kk] = hi;
                Wlo[n][kk] = lo;
            }
        } else {
            int n = tid & 63, kg = tid >> 6;
#pragma unroll
            for (int j = 0; j < 8; j++) {
                int kk = kg + j * 4;
                float w = W[(long long)(k0 + kk) * F + n];
                ushort hi = bf16_rne(w);
                ushort lo = bf16_rne(w - bf16_f(hi));
                Whi[n][kk] = hi;
                Wlo[n][kk] = lo;
            }
        }
        __syncthreads();

        short8 ah = *(const short8*)&Ahi[wave * 16 + l15][quad * 8];
        short8 al = *(const short8*)&Alo[wave * 16 + l15][quad * 8];
#pragma unroll
        for (int t = 0; t < NT; t++) {
            short8 bh = *(const short8*)&Whi[t * 16 + l15][quad * 8];
            short8 bl = *(const short8*)&Wlo[t * 16 + l15][quad * 8];
            acc[t] = __builtin_amdgcn_mfma_f32_16x16x32_bf16(ah, bh, acc[t], 0, 0, 0);
            acc[t] = __builtin_amdgcn_mfma_f32_16x16x32_bf16(ah, bl, acc[t], 0, 0, 0);
            acc[t] = __builtin_amdgcn_mfma_f32_16x16x32_bf16(al, bh, acc[t], 0, 0, 0);
        }
        __syncthreads();
    }

    // ---- epilogue: C[row=quad*4+r][col=t*16+l15] ----
    // attention vectors for this lane's columns
    float asl[NT], adl[NT];
#pragma unroll
    for (int t = 0; t < NT; t++) {
        asl[t] = asrc[t * 16 + l15];
        adl[t] = adst[t * 16 + l15];
    }
#pragma unroll
    for (int r = 0; r < 4; r++) {
        int grow = rowBase + wave * 16 + quad * 4 + r;
        // 1) bf16 message store (coalesced 2B/lane)
        if (grow < M) {
#pragma unroll
            for (int t = 0; t < NT; t++)
                xwb[(long long)grow * F + t * 16 + l15] = bf16_rne(acc[t][r]);
        }
        // 2) logits: per-head in-lane partials, then 16-lane butterfly
        float ps0 = 0.f, pd0 = 0.f, ps1 = 0.f, pd1 = 0.f;
#pragma unroll
        for (int t = 0; t < NT; t++) {
            float v = acc[t][r];
            if (H == 2 && t >= NT / 2) {
                ps1 = fmaf(v, asl[t], ps1);
                pd1 = fmaf(v, adl[t], pd1);
            } else {
                ps0 = fmaf(v, asl[t], ps0);
                pd0 = fmaf(v, adl[t], pd0);
            }
        }
#pragma unroll
        for (int off = 1; off < 16; off <<= 1) {
            ps0 += __shfl_xor(ps0, off);
            pd0 += __shfl_xor(pd0, off);
            if (H == 2) {
                ps1 += __shfl_xor(ps1, off);
                pd1 += __shfl_xor(pd1, off);
            }
        }
        if (l15 == 0 && grow < M) {
            al_s[grow * H + 0] = ps0;
            al_d[grow * H + 0] = pd0;
            if (H == 2) {
                al_s[grow * H + 1] = ps1;
                al_d[grow * H + 1] = pd1;
            }
        }
    }
}

// ---------------- per-dst-wave softmax aggregation (R8 verbatim) ------------
template <int F, int H>
__global__ __launch_bounds__(256) void k_agg(const uint* __restrict__ xwb,
                      const float* __restrict__ al_s,
                      const float* __restrict__ al_d, const int* __restrict__ row_start,
                      const int* __restrict__ col, const float* __restrict__ bias,
                      float* __restrict__ y, int n) {
    int wid = (blockIdx.x * blockDim.x + threadIdx.x) >> 6;  // one wave per dst
    int lane = threadIdx.x & 63;
    if (wid >= n) return;
    int beg = row_start[wid], end = row_start[wid + 1];

    float ald[H], m[H], l[H];
#pragma unroll
    for (int h = 0; h < H; h++) {
        ald[h] = al_d[wid * H + h];
        m[h] = -1e30f;
        l[h] = 0.f;
    }
    for (int e = beg + lane; e < end; e += 64) {
        int s = col[e];
#pragma unroll
        for (int h = 0; h < H; h++) {
            float ev = al_s[s * H + h] + ald[h];
            ev = (ev >= 0.f) ? ev : 0.2f * ev;
            if (ev > m[h]) {
                l[h] = l[h] * __expf(m[h] - ev) + 1.f;
                m[h] = ev;
            } else {
                l[h] += __expf(ev - m[h]);
            }
        }
    }
#pragma unroll
    for (int off = 32; off; off >>= 1) {
#pragma unroll
        for (int h = 0; h < H; h++) {
            float mo = __shfl_xor(m[h], off);
            float lo = __shfl_xor(l[h], off);
            float mn = fmaxf(m[h], mo);
            l[h] = l[h] * __expf(m[h] - mn) + lo * __expf(mo - mn);
            m[h] = mn;
        }
    }
    float inv[H];
#pragma unroll
    for (int h = 0; h < H; h++) inv[h] = 1.f / (l[h] + 1e-16f);

    float acc0 = 0.f, acc1 = 0.f;
    for (int base = beg; base < end; base += 64) {
        int nb = min(64, end - base);
        int ec = min(base + lane, end - 1);
        int s = col[ec];
        float a0, a1;
        {
            float av[H];
#pragma unroll
            for (int h = 0; h < H; h++) {
                float ev = al_s[s * H + h] + ald[h];
                ev = (ev >= 0.f) ? ev : 0.2f * ev;
                av[h] = __expf(ev - m[h]) * inv[h];
            }
            a0 = av[0];
            a1 = av[H - 1];
        }
        int j = 0;
        for (; j + 4 <= nb; j += 4) {
            int s0 = __shfl(s, j + 0), s1 = __shfl(s, j + 1);
            int s2 = __shfl(s, j + 2), s3 = __shfl(s, j + 3);
            float q00 = __shfl(a0, j + 0), q01 = __shfl(a1, j + 0);
            float q10 = __shfl(a0, j + 1), q11 = __shfl(a1, j + 1);
            float q20 = __shfl(a0, j + 2), q21 = __shfl(a1, j + 2);
            float q30 = __shfl(a0, j + 3), q31 = __shfl(a1, j + 3);
            float p0, p1, p2, p3;
            if (H == 2) {
                p0 = (lane < 32) ? q00 : q01;
                p1 = (lane < 32) ? q10 : q11;
                p2 = (lane < 32) ? q20 : q21;
                p3 = (lane < 32) ? q30 : q31;
            } else {
                p0 = q00; p1 = q10; p2 = q20; p3 = q30;
            }
            if (F == 128) {
                uint u0 = xwb[(s0 << 6) + lane];
                uint u1 = xwb[(s1 << 6) + lane];
                uint u2 = xwb[(s2 << 6) + lane];
                uint u3 = xwb[(s3 << 6) + lane];
                acc0 = fmaf(p0, __uint_as_float(u0 << 16), acc0);
                acc1 = fmaf(p0, __uint_as_float(u0 & 0xffff0000u), acc1);
                acc0 = fmaf(p1, __uint_as_float(u1 << 16), acc0);
                acc1 = fmaf(p1, __uint_as_float(u1 & 0xffff0000u), acc1);
                acc0 = fmaf(p2, __uint_as_float(u2 << 16), acc0);
                acc1 = fmaf(p2, __uint_as_float(u2 & 0xffff0000u), acc1);
                acc0 = fmaf(p3, __uint_as_float(u3 << 16), acc0);
                acc1 = fmaf(p3, __uint_as_float(u3 & 0xffff0000u), acc1);
            } else {
                int idx = lane >> 1;
                bool hi = (lane & 1) != 0;
                uint u0 = xwb[(s0 << 5) + idx];
                uint u1 = xwb[(s1 << 5) + idx];
                uint u2 = xwb[(s2 << 5) + idx];
                uint u3 = xwb[(s3 << 5) + idx];
                acc0 = fmaf(p0, __uint_as_float(hi ? (u0 & 0xffff0000u) : (u0 << 16)), acc0);
                acc0 = fmaf(p1, __uint_as_float(hi ? (u1 & 0xffff0000u) : (u1 << 16)), acc0);
                acc0 = fmaf(p2, __uint_as_float(hi ? (u2 & 0xffff0000u) : (u2 << 16)), acc0);
                acc0 = fmaf(p3, __uint_as_float(hi ? (u3 & 0xffff0000u) : (u3 << 16)), acc0);
            }
        }
        for (; j < nb; ++j) {
            int sj = __shfl(s, j);
            float q0 = __shfl(a0, j);
            float q1 = __shfl(a1, j);
            float alpha;
            if (H == 2) {
                alpha = (lane < 32) ? q0 : q1;
            } else {
                alpha = q0;
            }
            if (F == 128) {
                uint u = xwb[(sj << 6) + lane];
                acc0 = fmaf(alpha, __uint_as_float(u << 16), acc0);
                acc1 = fmaf(alpha, __uint_as_float(u & 0xffff0000u), acc1);
            } else {
                uint u = xwb[(sj << 5) + (lane >> 1)];
                acc0 = fmaf(alpha, __uint_as_float((lane & 1) ? (u & 0xffff0000u) : (u << 16)), acc0);
            }
        }
    }
    if (F == 128) {
        float2 o;
        o.x = fmaxf(acc0 + bias[2 * lane], 0.f);
        o.y = fmaxf(acc1 + bias[2 * lane + 1], 0.f);
        ((float2*)y)[(long long)wid * 64 + lane] = o;
    } else {
        y[(long long)wid * 64 + lane] = fmaxf(acc0 + bias[lane], 0.f);
    }
}

// ---------------- BatchNorm (R8 verbatim) ----------------
template <int F>
__global__ void k_bn_stats(const float* __restrict__ y, float* __restrict__ sums, int n) {
    constexpr int C4 = F / 4;
    constexpr int NPB = 256 / C4;
    int c4 = threadIdx.x % C4;
    int sub = threadIdx.x / C4;
    float4 s = {0, 0, 0, 0}, s2 = {0, 0, 0, 0};
    for (int node = blockIdx.x * NPB + sub; node < n; node += gridDim.x * NPB) {
        float4 v = ((const float4*)y)[node * C4 + c4];
        s.x += v.x; s.y += v.y; s.z += v.z; s.w += v.w;
        s2.x += v.x * v.x; s2.y += v.y * v.y; s2.z += v.z * v.z; s2.w += v.w * v.w;
    }
    __shared__ float4 ls[256], ls2[256];
    ls[threadIdx.x] = s;
    ls2[threadIdx.x] = s2;
    __syncthreads();
    if (sub == 0) {
#pragma unroll
        for (int k = 1; k < NPB; k++) {
            float4 t = ls[c4 + k * C4], t2 = ls2[c4 + k * C4];
            s.x += t.x; s.y += t.y; s.z += t.z; s.w += t.w;
            s2.x += t2.x; s2.y += t2.y; s2.z += t2.z; s2.w += t2.w;
        }
        atomicAdd(&sums[c4 * 4 + 0], s.x);
        atomicAdd(&sums[c4 * 4 + 1], s.y);
        atomicAdd(&sums[c4 * 4 + 2], s.z);
        atomicAdd(&sums[c4 * 4 + 3], s.w);
        atomicAdd(&sums[F + c4 * 4 + 0], s2.x);
        atomicAdd(&sums[F + c4 * 4 + 1], s2.y);
        atomicAdd(&sums[F + c4 * 4 + 2], s2.z);
        atomicAdd(&sums[F + c4 * 4 + 3], s2.w);
    }
}

template <int F>
__global__ void k_bn_prep(const float* __restrict__ sums, const float* __restrict__ g,
                          const float* __restrict__ be, float* __restrict__ sc,
                          float* __restrict__ sh, float invN) {
    int ch = threadIdx.x;
    if (ch < F) {
        float mean = sums[ch] * invN;
        float var = sums[F + ch] * invN - mean * mean;
        float s = g[ch] * rsqrtf(var + 1e-5f);
        sc[ch] = s;
        sh[ch] = be[ch] - mean * s;
    }
}

template <int F>
__global__ void k_bn_apply(const float* __restrict__ y, const float* __restrict__ sc,
                           const float* __restrict__ sh, float* __restrict__ outp, int n) {
    constexpr int C4 = F / 4;
    int t = blockIdx.x * blockDim.x + threadIdx.x;
    if (t >= n * C4) return;
    int node = t / C4, c4 = t % C4;
    float4 v = ((const float4*)y)[t];
    float4 o;
    o.x = v.x * sc[c4 * 4 + 0] + sh[c4 * 4 + 0];
    o.y = v.y * sc[c4 * 4 + 1] + sh[c4 * 4 + 1];
    o.z = v.z * sc[c4 * 4 + 2] + sh[c4 * 4 + 2];
    o.w = v.w * sc[c4 * 4 + 3] + sh[c4 * 4 + 3];
    ((float4*)(outp + (long long)node * 320))[c4] = o;
}

// ---------------------------------------------------------------------------
extern "C" void kernel_launch(void* const* d_in, const int* in_sizes, int n_in,
                              void* d_out, int out_size, void* d_ws, size_t ws_size,
                              hipStream_t stream) {
    const float* x   = (const float*)d_in[0];
    const int*   adj = (const int*)d_in[1];
    const float* W1  = (const float*)d_in[2];
    const float* as1 = (const float*)d_in[3];
    const float* ad1 = (const float*)d_in[4];
    const float* b1  = (const float*)d_in[5];
    const float* g1  = (const float*)d_in[6];
    const float* be1 = (const float*)d_in[7];
    const float* W2  = (const float*)d_in[8];
    const float* as2 = (const float*)d_in[9];
    const float* ad2 = (const float*)d_in[10];
    const float* b2  = (const float*)d_in[11];
    const float* g2  = (const float*)d_in[12];
    const float* be2 = (const float*)d_in[13];
    const float* W3  = (const float*)d_in[14];
    const float* as3 = (const float*)d_in[15];
    const float* ad3 = (const float*)d_in[16];
    const float* b3  = (const float*)d_in[17];
    const float* g3  = (const float*)d_in[18];
    const float* be3 = (const float*)d_in[19];
    float* out = (float*)d_out;

    const int N = in_sizes[0] / 128;
    const int E = in_sizes[1] / 2;

    // workspace (fp32 xw is gone)
    float* ws    = (float*)d_ws;
    float* ybuf  = ws;                          // N*128
    float* al_s  = ybuf + (size_t)N * 128;      // N*2
    float* al_d  = al_s + (size_t)N * 2;        // N*2
    float* stats = al_d + (size_t)N * 2;        // 256
    float* scb   = stats + 256;                 // 128
    float* shb   = scb + 128;                   // 128
    uint* xwb    = (uint*)(shb + 128);          // N*64 uints (bf16x2)
    int* deg       = (int*)(xwb + (size_t)N * 64);  // N (reused as cursor)
    int* row_start = deg + N;                   // N+1
    int* btot      = row_start + (N + 1);       // 64
    int* col       = btot + 64;                 // E+N

    const int* esrc = adj;
    const int* edst = adj + E;

    const int B = 256;
    auto cdiv = [](int a, int b) { return (a + b - 1) / b; };

    // ---- CSR build ----
    k_set1<<<cdiv(N, B), B, 0, stream>>>(deg, N);
    k_deg_count<<<cdiv(E, B), B, 0, stream>>>(edst, E, deg);
    int nsb = cdiv(N, 1024);
    k_scan1<<<nsb, 1024, 0, stream>>>(deg, row_start, btot, N);
    k_scan2<<<1, 64, 0, stream>>>(btot, nsb, row_start, N);
    k_scan3<<<nsb, 1024, 0, stream>>>(row_start, btot, N);
    k_copy_int<<<cdiv(N, B), B, 0, stream>>>(row_start, deg, N);   // deg = cursor
    k_fill<<<cdiv(E + N, B), B, 0, stream>>>(esrc, edst, E, N, deg, col);

    const float invN = 1.f / (float)N;
    ushort* xwb_us = (ushort*)xwb;

    // ---- layer 1: 128 -> 128 (H=2) ----
    k_gemm<128, 2, false><<<cdiv(N, 64), B, 0, stream>>>(x, W1, nullptr, nullptr,
                                                         as1, ad1, xwb_us, al_s, al_d, N);
    k_agg<128, 2><<<cdiv(N, 4), B, 0, stream>>>(xwb, al_s, al_d, row_start, col, b1, ybuf, N);
    hipMemsetAsync(stats, 0, 256 * sizeof(float), stream);
    k_bn_stats<128><<<256, B, 0, stream>>>(ybuf, stats, N);
    k_bn_prep<128><<<1, 128, 0, stream>>>(stats, g1, be1, scb, shb, invN);
    k_bn_apply<128><<<cdiv(N * 32, B), B, 0, stream>>>(ybuf, scb, shb, out + 0, N);

    // ---- layer 2: 128 -> 128 (H=2) ----
    k_gemm<128, 2, true><<<cdiv(N, 64), B, 0, stream>>>(ybuf, W2, scb, shb,
                                                        as2, ad2, xwb_us, al_s, al_d, N);
    k_agg<128, 2><<<cdiv(N, 4), B, 0, stream>>>(xwb, al_s, al_d, row_start, col, b2, ybuf, N);
    hipMemsetAsync(stats, 0, 256 * sizeof(float), stream);
    k_bn_stats<128><<<256, B, 0, stream>>>(ybuf, stats, N);
    k_bn_prep<128><<<1, 128, 0, stream>>>(stats, g2, be2, scb, shb, invN);
    k_bn_apply<128><<<cdiv(N * 32, B), B, 0, stream>>>(ybuf, scb, shb, out + 128, N);

    // ---- layer 3: 128 -> 64 (H=1) ----
    k_gemm<64, 1, true><<<cdiv(N, 64), B, 0, stream>>>(ybuf, W3, scb, shb,
                                                       as3, ad3, xwb_us, al_s, al_d, N);
    k_agg<64, 1><<<cdiv(N, 4), B, 0, stream>>>(xwb, al_s, al_d, row_start, col, b3, ybuf, N);
    hipMemsetAsync(stats, 0, 256 * sizeof(float), stream);
    k_bn_stats<64><<<256, B, 0, stream>>>(ybuf, stats, N);
    k_bn_prep<64><<<1, 64, 0, stream>>>(stats, g3, be3, scb, shb, invN);
    k_bn_apply<64><<<cdiv(N * 16, B), B, 0, stream>>>(ybuf, scb, shb, out + 256, N);
}